// Round 2
// baseline (603.642 us; speedup 1.0000x reference)
//
#include <hip/hip_runtime.h>
#include <hip/hip_bf16.h>
#include <stdint.h>

typedef __bf16 bf16;
typedef __bf16 bf16x4 __attribute__((ext_vector_type(4)));
typedef __bf16 bf16x8 __attribute__((ext_vector_type(8)));
typedef float f32x4 __attribute__((ext_vector_type(4)));
typedef float f32x16 __attribute__((ext_vector_type(16)));

#define N_HEADS 16
#define HEAD_DIM 128
#define SEQ 2048
#define DIM 2048
#define BATCH 2
#define MROWS (BATCH * SEQ)          // 4096
#define NQKV (3 * DIM)               // 6144
#define SM_SCALE 0.08838834764831845f  // 1/sqrt(128)
#define SMAX 24.0f                     // static softmax max

__device__ __forceinline__ bf16 f2b(float f) {
  union { __hip_bfloat16 h; bf16 b; } u;
  u.h = __float2bfloat16(f);
  return u.b;
}

__device__ __forceinline__ uint32_t pack2(float a, float b) {
  union { __hip_bfloat16 h; unsigned short s; } ua, ub;
  ua.h = __float2bfloat16(a); ub.h = __float2bfloat16(b);
  return (uint32_t)ua.s | ((uint32_t)ub.s << 16);   // a in low 16 (even k)
}

// async global->LDS (GEMMs only; lane-contiguous source, the m97 pattern)
__device__ __forceinline__ void async16(const bf16* g, bf16* l) {
  __builtin_amdgcn_global_load_lds(
      (__attribute__((address_space(1))) void*)(uintptr_t)g,
      (__attribute__((address_space(3))) void*)(uintptr_t)l,
      16, 0, 0);
}

// ---------------------------------------------------------------- cvt f32->bf16
__global__ __launch_bounds__(256) void cvt_kernel(const float* __restrict__ src,
                                                  bf16* __restrict__ dst, int n) {
  int i = (blockIdx.x * 256 + threadIdx.x) * 8;
  if (i >= n) return;
  float4 a = *(const float4*)(src + i);
  float4 b = *(const float4*)(src + i + 4);
  bf16x8 o;
  o[0] = f2b(a.x); o[1] = f2b(a.y); o[2] = f2b(a.z); o[3] = f2b(a.w);
  o[4] = f2b(b.x); o[5] = f2b(b.y); o[6] = f2b(b.z); o[7] = f2b(b.w);
  *(bf16x8*)(dst + i) = o;
}

// fused cvt of the 4 weight matrices; w0..w2 -> wqkv, w3 -> wo
__global__ __launch_bounds__(256) void cvt_w4(const float* __restrict__ w0,
                                              const float* __restrict__ w1,
                                              const float* __restrict__ w2,
                                              const float* __restrict__ w3,
                                              bf16* __restrict__ wqkv,
                                              bf16* __restrict__ wo) {
  const int per = (DIM * DIM) / 8 / 256;
  int which = blockIdx.x / per;
  int i = (blockIdx.x % per) * 256 * 8 + threadIdx.x * 8;
  const float* src = which == 0 ? w0 : which == 1 ? w1 : which == 2 ? w2 : w3;
  bf16* dst = which < 3 ? wqkv + (size_t)which * DIM * DIM : wo;
  float4 a = *(const float4*)(src + i);
  float4 b = *(const float4*)(src + i + 4);
  bf16x8 o;
  o[0] = f2b(a.x); o[1] = f2b(a.y); o[2] = f2b(a.z); o[3] = f2b(a.w);
  o[4] = f2b(b.x); o[5] = f2b(b.y); o[6] = f2b(b.z); o[7] = f2b(b.w);
  *(bf16x8*)(dst + i) = o;
}

// ------------------------------------------------- m97-style 128x128x32 mainloop
__device__ __forceinline__ void gemm_tile_mainloop(
    const bf16* __restrict__ A, const bf16* __restrict__ Bw, int K,
    int rowBase, int colBase, bf16* lA, bf16* lB, f32x4 acc[4][4]) {
  const int t = threadIdx.x;
  const int w = t >> 6, lane = t & 63;
  const int lm = lane & 15, quad = lane >> 4;
  const int wr = (w >> 1) * 64, wc = (w & 1) * 64;

  for (int kt = 0; kt < K; kt += 32) {
#pragma unroll
    for (int i = 0; i < 2; i++) {
      const int c = i * 256 + t;
      const int r = c >> 2, cc = (c & 3) << 3;
      async16(A + (size_t)(rowBase + r) * K + (kt + cc), lA + (i * 256 + w * 64) * 8);
      async16(Bw + (size_t)(colBase + r) * K + (kt + cc), lB + (i * 256 + w * 64) * 8);
    }
    asm volatile("s_waitcnt vmcnt(0)" ::: "memory");
    __syncthreads();
    bf16x8 af[4], bfr[4];
#pragma unroll
    for (int f = 0; f < 4; f++)
      af[f] = *(const bf16x8*)(lA + (wr + f * 16 + lm) * 32 + quad * 8);
#pragma unroll
    for (int f = 0; f < 4; f++)
      bfr[f] = *(const bf16x8*)(lB + (wc + f * 16 + lm) * 32 + quad * 8);
#pragma unroll
    for (int fr = 0; fr < 4; fr++)
#pragma unroll
      for (int fc = 0; fc < 4; fc++)
        acc[fr][fc] = __builtin_amdgcn_mfma_f32_16x16x32_bf16(af[fr], bfr[fc], acc[fr][fc], 0, 0, 0);
    __syncthreads();
  }
}

// QKV projection: Q,K -> [B,H,S,Dh]; V -> TRANSPOSED [B,H,Dh,S]
__global__ __launch_bounds__(256) void gemm_qkv(const bf16* __restrict__ X,
                                                const bf16* __restrict__ W,
                                                bf16* __restrict__ Q,
                                                bf16* __restrict__ Kv,
                                                bf16* __restrict__ VT) {
  __shared__ __align__(16) bf16 lA[128 * 32];
  __shared__ __align__(16) bf16 lB[128 * 32];
  f32x4 acc[4][4];
  f32x4 z = {0.f, 0.f, 0.f, 0.f};
#pragma unroll
  for (int i = 0; i < 4; i++)
#pragma unroll
    for (int j = 0; j < 4; j++) acc[i][j] = z;

  const int rowBase = blockIdx.y * 128, colBase = blockIdx.x * 128;
  gemm_tile_mainloop(X, W, DIM, rowBase, colBase, lA, lB, acc);

  const int t = threadIdx.x, w = t >> 6, lane = t & 63;
  const int lm = lane & 15, quad = lane >> 4;
  const int wr = (w >> 1) * 64, wc = (w & 1) * 64;
  const int which = colBase >> 11;  // 0=Q 1=K 2=V
  if (which < 2) {
    bf16* dst = which ? Kv : Q;
#pragma unroll
    for (int fr = 0; fr < 4; fr++)
#pragma unroll
      for (int fc = 0; fc < 4; fc++)
#pragma unroll
        for (int r = 0; r < 4; r++) {
          int m = rowBase + wr + fr * 16 + quad * 4 + r;
          int n = (colBase + wc + fc * 16 + lm) & 2047;
          int h = n >> 7, d = n & 127;
          int b = m >> 11, s = m & 2047;
          dst[(((size_t)(b * N_HEADS + h) * SEQ) + s) * HEAD_DIM + d] = f2b(acc[fr][fc][r]);
        }
  } else {
#pragma unroll
    for (int fr = 0; fr < 4; fr++)
#pragma unroll
      for (int fc = 0; fc < 4; fc++) {
        int n = (colBase + wc + fc * 16 + lm) & 2047;
        int h = n >> 7, d = n & 127;
        int m = rowBase + wr + fr * 16 + quad * 4;
        int b = m >> 11, s = m & 2047;
        bf16x4 pk;
#pragma unroll
        for (int r = 0; r < 4; r++) pk[r] = f2b(acc[fr][fc][r]);
        *(bf16x4*)&VT[((size_t)(b * N_HEADS + h) * HEAD_DIM + d) * SEQ + s] = pk;
      }
  }
}

// Output projection
__global__ __launch_bounds__(256) void gemm_out(const bf16* __restrict__ A,
                                                const bf16* __restrict__ W,
                                                float* __restrict__ out) {
  __shared__ __align__(16) bf16 lA[128 * 32];
  __shared__ __align__(16) bf16 lB[128 * 32];
  f32x4 acc[4][4];
  f32x4 z = {0.f, 0.f, 0.f, 0.f};
#pragma unroll
  for (int i = 0; i < 4; i++)
#pragma unroll
    for (int j = 0; j < 4; j++) acc[i][j] = z;

  const int rowBase = blockIdx.y * 128, colBase = blockIdx.x * 128;
  gemm_tile_mainloop(A, W, DIM, rowBase, colBase, lA, lB, acc);

  const int t = threadIdx.x, w = t >> 6, lane = t & 63;
  const int lm = lane & 15, quad = lane >> 4;
  const int wr = (w >> 1) * 64, wc = (w & 1) * 64;
#pragma unroll
  for (int fr = 0; fr < 4; fr++)
#pragma unroll
    for (int fc = 0; fc < 4; fc++)
#pragma unroll
      for (int r = 0; r < 4; r++) {
        int m = rowBase + wr + fr * 16 + quad * 4 + r;
        int n = colBase + wc + fc * 16 + lm;
        out[(size_t)m * DIM + n] = acc[fr][fc][r];
      }
}

// --------------------------------------------- RMSNorm + RoPE (in place on q,k)
__global__ __launch_bounds__(256) void norm_rope(bf16* __restrict__ Q,
                                                 bf16* __restrict__ K,
                                                 const float* __restrict__ rope,
                                                 const float* __restrict__ qw,
                                                 const float* __restrict__ kw) {
  const int t = threadIdx.x, w = t >> 6, lane = t & 63;
  const int rid = blockIdx.x * 4 + w;
  const int which = rid >> 16;          // 0 = q, 1 = k
  const int row = rid & 65535;          // (b*16+h)*2048 + s
  bf16* ptr = (which ? K : Q) + (size_t)row * HEAD_DIM;
  const float* nw = which ? kw : qw;
  const int s = row & (SEQ - 1);

  float x0 = (float)ptr[lane];
  float x1 = (float)ptr[lane + 64];
  float ss = x0 * x0 + x1 * x1;
#pragma unroll
  for (int off = 32; off; off >>= 1) ss += __shfl_xor(ss, off);
  float r = rsqrtf(ss * (1.f / 128.f) + 1e-6f);
  float x0n = x0 * r * nw[lane];
  float x1n = x1 * r * nw[lane + 64];
  float4 f = ((const float4*)rope)[s * 64 + lane];
  float y0 = f.x * x0n + f.y * x1n;
  float y1 = f.z * x0n + f.w * x1n;
  if (!which) { y0 *= SM_SCALE; y1 *= SM_SCALE; }
  ptr[lane] = f2b(y0);
  ptr[lane + 64] = f2b(y1);
}

// --------------------------------------------------------- flash attention v7
// grid (bh=32, qt=16): bh%8 pins all q-tile blocks of a (b,h) to one XCD (L2
// capture of K+V — verified: FETCH 317->57 MB). Block 256 = 4 waves:
// wave = (qh = w>>1, kb = w&1); Br=128 (2 reg q-sets of 32), Bc=64, 32-row
// k-band per wave. Staging = coalesced global b128 -> VGPR -> swizzled
// ds_write (R1 post-mortem: direct-from-L2 frag loads are latency-serialized
// at 2 waves/SIMD — LDS staging IS the pipeline; keep it).
// v7 vs v5: K/V LDS is DOUBLE-BUFFERED (32->64 KB, still 2 blocks/CU) so the
// per-tile chain needs ONE __syncthreads instead of two: iter j writes
// buf[j&1] (regs staged in iter j-1, full-iteration latency hiding), one
// barrier, then computes buf[j&1] while next tile's global loads fly.
// Write-vs-read hazard on a buffer is separated by the PREVIOUS iteration's
// barrier. T5 s_setprio(1) wraps both MFMA clusters (attn +4-7%, m191).
__global__ __launch_bounds__(256, 2) void attn_kernel(const bf16* __restrict__ Q,
                                                      const bf16* __restrict__ K,
                                                      const bf16* __restrict__ VT,
                                                      bf16* __restrict__ O) {
  __shared__ __align__(16) bf16 Ks[2][64 * 128];   // [buf][kr][chunk ^ (kr&15)]
  __shared__ __align__(16) bf16 Vs[2][128 * 64];   // [buf][d][chunk ^ (d&7)]

  const int t = threadIdx.x, w = t >> 6, lane = t & 63;
  const int lq = lane & 31, h = lane >> 5;
  const int qh = w >> 1, kb = w & 1;
  const int bh = blockIdx.x, qt = blockIdx.y;

  // hoisted Q B-frags, 2 q-sets of 32 rows
  bf16x8 qf[2][8];
#pragma unroll
  for (int qs = 0; qs < 2; qs++) {
    const bf16* Qp = Q + ((size_t)bh * SEQ + qt * 128 + qh * 64 + qs * 32 + lq) * HEAD_DIM;
#pragma unroll
    for (int ks = 0; ks < 8; ks++)
      qf[qs][ks] = *(const bf16x8*)(Qp + ks * 16 + h * 8);
  }

  f32x16 oacc[2][4];
#pragma unroll
  for (int qs = 0; qs < 2; qs++)
#pragma unroll
    for (int nb = 0; nb < 4; nb++)
#pragma unroll
      for (int e = 0; e < 16; e++) oacc[qs][nb][e] = 0.f;
  float rsum[2] = {0.f, 0.f};

  const bf16* kbase = K + (size_t)bh * SEQ * HEAD_DIM;
  const bf16* vbase = VT + (size_t)bh * HEAD_DIM * SEQ;
  const int kr = kb * 32 + lq;

  // staging registers + index helpers (per wave: 16 K-rows, 32 V-rows)
  const int krow = w * 16 + (lane >> 4), kcc = lane & 15;        // K: 4 rows/instr
  const int vrow = w * 32 + (lane >> 3), vcc = lane & 7;         // V: 8 rows/instr
  bf16x8 kreg[4], vreg[4];

  auto load_tile = [&](int j) {
    const bf16* kp = kbase + (size_t)j * 64 * HEAD_DIM;
    const bf16* vp = vbase + j * 64;
#pragma unroll
    for (int i = 0; i < 4; i++)
      kreg[i] = *(const bf16x8*)(kp + (krow + i * 4) * HEAD_DIM + kcc * 8);
#pragma unroll
    for (int i = 0; i < 4; i++)
      vreg[i] = *(const bf16x8*)(vp + (size_t)(vrow + i * 8) * SEQ + vcc * 8);
  };

  auto store_tile = [&](int buf) {
#pragma unroll
    for (int i = 0; i < 4; i++) {
      int r = krow + i * 4;
      *(bf16x8*)&Ks[buf][r * 128 + ((kcc ^ (r & 15)) << 3)] = kreg[i];
    }
#pragma unroll
    for (int i = 0; i < 4; i++) {
      int d = vrow + i * 8;
      *(bf16x8*)&Vs[buf][d * 64 + ((vcc ^ (d & 7)) << 3)] = vreg[i];
    }
  };

  load_tile(0);

  for (int j = 0; j < SEQ / 64; j++) {
    const int buf = j & 1;
    // write staged regs (tile j, loaded last iteration) into buf
    store_tile(buf);
    __syncthreads();   // the ONLY barrier per tile

    // issue next tile's global loads; they land during this tile's compute
    if (j + 1 < SEQ / 64) load_tile(j + 1);

    // S^T = K Q^T on this wave's 32-row K-band; each kf feeds both q-sets
    f32x16 sacc[2];
#pragma unroll
    for (int qs = 0; qs < 2; qs++)
#pragma unroll
      for (int e = 0; e < 16; e++) sacc[qs][e] = -SMAX;  // bias so p = exp(sacc)
    __builtin_amdgcn_s_setprio(1);
#pragma unroll
    for (int ks = 0; ks < 8; ks++) {
      int c = ks * 2 + h;
      bf16x8 kf = *(const bf16x8*)&Ks[buf][kr * 128 + ((c ^ (kr & 15)) << 3)];
      sacc[0] = __builtin_amdgcn_mfma_f32_32x32x16_bf16(kf, qf[0][ks], sacc[0], 0, 0, 0);
      sacc[1] = __builtin_amdgcn_mfma_f32_32x32x16_bf16(kf, qf[1][ks], sacc[1], 0, 0, 0);
    }
    __builtin_amdgcn_s_setprio(0);

    // exp + pack + in-register C->A transform (cross-half shfl_xor)
    uint32_t a1[2][4], a2[2][4];
#pragma unroll
    for (int qs = 0; qs < 2; qs++) {
      float e[16];
#pragma unroll
      for (int r = 0; r < 16; r++) {
        e[r] = __expf(sacc[qs][r]);
        rsum[qs] += e[r];
      }
      uint32_t pk[8];
#pragma unroll
      for (int i = 0; i < 8; i++) pk[i] = pack2(e[2 * i], e[2 * i + 1]);
      uint32_t ta = h ? pk[0] : pk[2], tb = h ? pk[1] : pk[3];
      uint32_t tc = h ? pk[4] : pk[6], td = h ? pk[5] : pk[7];
      uint32_t ra = __shfl_xor((int)ta, 32), rb = __shfl_xor((int)tb, 32);
      uint32_t rc = __shfl_xor((int)tc, 32), rd = __shfl_xor((int)td, 32);
      a1[qs][0] = h ? ra : pk[0]; a1[qs][1] = h ? rb : pk[1];
      a1[qs][2] = h ? pk[2] : ra; a1[qs][3] = h ? pk[3] : rb;
      a2[qs][0] = h ? rc : pk[4]; a2[qs][1] = h ? rd : pk[5];
      a2[qs][2] = h ? pk[6] : rc; a2[qs][3] = h ? pk[7] : rd;
    }

    // O += P V on this wave's K-band; each bv feeds both q-sets
    __builtin_amdgcn_s_setprio(1);
#pragma unroll
    for (int ks2 = 0; ks2 < 2; ks2++) {
      union { uint32_t u[4]; bf16x8 v; } ap0, ap1;
#pragma unroll
      for (int i = 0; i < 4; i++) {
        ap0.u[i] = ks2 ? a2[0][i] : a1[0][i];
        ap1.u[i] = ks2 ? a2[1][i] : a1[1][i];
      }
      int c2 = kb * 4 + ks2 * 2 + h;
#pragma unroll
      for (int nb = 0; nb < 4; nb++) {
        int rv = nb * 32 + lq;
        bf16x8 bv = *(const bf16x8*)&Vs[buf][rv * 64 + ((c2 ^ (rv & 7)) << 3)];
        oacc[0][nb] = __builtin_amdgcn_mfma_f32_32x32x16_bf16(ap0.v, bv, oacc[0][nb], 0, 0, 0);
        oacc[1][nb] = __builtin_amdgcn_mfma_f32_32x32x16_bf16(ap1.v, bv, oacc[1][nb], 0, 0, 0);
      }
    }
    __builtin_amdgcn_s_setprio(0);
    // no trailing barrier: next iteration writes the OTHER buffer; the
    // write-after-read hazard on THIS buffer is fenced by next iter's barrier
  }

  // ---- epilogue: merge kb pairs via LDS (alias buf0 regions, which the
  // final iteration j=31 does not read: it computes on buf1), normalize, store
  rsum[0] += __shfl_xor(rsum[0], 32);
  rsum[1] += __shfl_xor(rsum[1], 32);
  float* Om = (float*)&Ks[0][0];   // [pair][64 q][32 d] f32 = 16 KB
  float* Rs = (float*)&Vs[0][0];   // [pair][qs][32] f32
  const int pair = qh;
  const int b = bh >> 4, hh = bh & 15;
  float inv[2] = {0.f, 0.f};

#pragma unroll
  for (int nb = 0; nb < 4; nb++) {
    if (kb == 1) {
      if (nb == 0 && h == 0) {
        Rs[(pair * 2 + 0) * 32 + lq] = rsum[0];
        Rs[(pair * 2 + 1) * 32 + lq] = rsum[1];
      }
#pragma unroll
      for (int qs = 0; qs < 2; qs++)
#pragma unroll
        for (int r = 0; r < 16; r++) {
          int rowm = (r & 3) + 8 * (r >> 2) + 4 * h;
          Om[(pair * 64 + qs * 32 + rowm) * 32 + lq] = oacc[qs][nb][r];
        }
    }
    __syncthreads();
    if (kb == 0) {
      if (nb == 0) {
        inv[0] = 1.f / (rsum[0] + Rs[(pair * 2 + 0) * 32 + lq]);
        inv[1] = 1.f / (rsum[1] + Rs[(pair * 2 + 1) * 32 + lq]);
      }
#pragma unroll
      for (int qs = 0; qs < 2; qs++)
#pragma unroll
        for (int r = 0; r < 16; r++) {
          int rowm = (r & 3) + 8 * (r >> 2) + 4 * h;
          float val = oacc[qs][nb][r] + Om[(pair * 64 + qs * 32 + rowm) * 32 + lq];
          float iv = __shfl(inv[qs], rowm);
          int qg = qt * 128 + qh * 64 + qs * 32 + rowm;
          O[((size_t)b * SEQ + qg) * DIM + hh * HEAD_DIM + nb * 32 + lq] = f2b(val * iv);
        }
    }
    __syncthreads();
  }
}

extern "C" void kernel_launch(void* const* d_in, const int* in_sizes, int n_in,
                              void* d_out, int out_size, void* d_ws, size_t ws_size,
                              hipStream_t stream) {
  const float* x    = (const float*)d_in[0];
  const float* rope = (const float*)d_in[1];
  const float* Wq   = (const float*)d_in[2];
  const float* Wk   = (const float*)d_in[3];
  const float* Wv   = (const float*)d_in[4];
  const float* Wo   = (const float*)d_in[5];
  const float* qw   = (const float*)d_in[6];
  const float* kw   = (const float*)d_in[7];
  float* out = (float*)d_out;

  char* ws = (char*)d_ws;
  bf16* xb   = (bf16*)ws;                        // 16 MB; reused as attn-out
  bf16* wqkv = (bf16*)(ws + (16u << 20));        // 24 MB
  bf16* wo   = (bf16*)(ws + (40u << 20));        // 8 MB
  bf16* qb   = (bf16*)(ws + (48u << 20));        // 16 MB [B,H,S,Dh]
  bf16* kb   = (bf16*)(ws + (64u << 20));        // 16 MB [B,H,S,Dh]
  bf16* vt   = (bf16*)(ws + (80u << 20));        // 16 MB [B,H,Dh,S]
  bf16* attn = xb;

  const int NX = MROWS * DIM;
  const int NW = DIM * DIM;

  cvt_kernel<<<NX / 8 / 256, 256, 0, stream>>>(x, xb, NX);
  cvt_w4<<<4 * (NW / 8 / 256), 256, 0, stream>>>(Wq, Wk, Wv, Wo, wqkv, wo);

  gemm_qkv<<<dim3(NQKV / 128, MROWS / 128), 256, 0, stream>>>(xb, wqkv, qb, kb, vt);
  norm_rope<<<(2 * BATCH * N_HEADS * SEQ) / 4, 256, 0, stream>>>(qb, kb, rope, qw, kw);
  attn_kernel<<<dim3(BATCH * N_HEADS, SEQ / 128), 256, 0, stream>>>(qb, kb, vt, attn);
  gemm_out<<<dim3(DIM / 128, MROWS / 128), 256, 0, stream>>>(attn, wo, out);
}

// Round 3
// 464.393 us; speedup vs baseline: 1.2999x; 1.2999x over previous
//
#include <hip/hip_runtime.h>
#include <hip/hip_bf16.h>
#include <stdint.h>

typedef __bf16 bf16;
typedef __bf16 bf16x4 __attribute__((ext_vector_type(4)));
typedef __bf16 bf16x8 __attribute__((ext_vector_type(8)));
typedef float f32x4 __attribute__((ext_vector_type(4)));
typedef float f32x16 __attribute__((ext_vector_type(16)));

#define N_HEADS 16
#define HEAD_DIM 128
#define SEQ 2048
#define DIM 2048
#define BATCH 2
#define MROWS (BATCH * SEQ)          // 4096
#define NQKV (3 * DIM)               // 6144
#define SM_SCALE 0.08838834764831845f   // 1/sqrt(128)
// exp2-domain softmax: Q pre-scaled by SM_SCALE*log2(e); bias = SMAX*log2(e)
#define QSCALE_L2E 0.12751743343563824f // SM_SCALE * 1.4426950408889634
#define SMAX_L2E 34.624680981335122f    // 24.0 * log2(e)

__device__ __forceinline__ bf16 f2b(float f) {
  union { __hip_bfloat16 h; bf16 b; } u;
  u.h = __float2bfloat16(f);
  return u.b;
}

__device__ __forceinline__ uint32_t pack2(float a, float b) {
  union { __hip_bfloat16 h; unsigned short s; } ua, ub;
  ua.h = __float2bfloat16(a); ub.h = __float2bfloat16(b);
  return (uint32_t)ua.s | ((uint32_t)ub.s << 16);   // a in low 16 (even k)
}

// async global->LDS (GEMMs only; lane-contiguous source, the m97 pattern)
__device__ __forceinline__ void async16(const bf16* g, bf16* l) {
  __builtin_amdgcn_global_load_lds(
      (__attribute__((address_space(1))) void*)(uintptr_t)g,
      (__attribute__((address_space(3))) void*)(uintptr_t)l,
      16, 0, 0);
}

// ---------------------------------------------------------------- cvt f32->bf16
__global__ __launch_bounds__(256) void cvt_kernel(const float* __restrict__ src,
                                                  bf16* __restrict__ dst, int n) {
  int i = (blockIdx.x * 256 + threadIdx.x) * 8;
  if (i >= n) return;
  float4 a = *(const float4*)(src + i);
  float4 b = *(const float4*)(src + i + 4);
  bf16x8 o;
  o[0] = f2b(a.x); o[1] = f2b(a.y); o[2] = f2b(a.z); o[3] = f2b(a.w);
  o[4] = f2b(b.x); o[5] = f2b(b.y); o[6] = f2b(b.z); o[7] = f2b(b.w);
  *(bf16x8*)(dst + i) = o;
}

// fused cvt of the 4 weight matrices; w0..w2 -> wqkv, w3 -> wo
__global__ __launch_bounds__(256) void cvt_w4(const float* __restrict__ w0,
                                              const float* __restrict__ w1,
                                              const float* __restrict__ w2,
                                              const float* __restrict__ w3,
                                              bf16* __restrict__ wqkv,
                                              bf16* __restrict__ wo) {
  const int per = (DIM * DIM) / 8 / 256;
  int which = blockIdx.x / per;
  int i = (blockIdx.x % per) * 256 * 8 + threadIdx.x * 8;
  const float* src = which == 0 ? w0 : which == 1 ? w1 : which == 2 ? w2 : w3;
  bf16* dst = which < 3 ? wqkv + (size_t)which * DIM * DIM : wo;
  float4 a = *(const float4*)(src + i);
  float4 b = *(const float4*)(src + i + 4);
  bf16x8 o;
  o[0] = f2b(a.x); o[1] = f2b(a.y); o[2] = f2b(a.z); o[3] = f2b(a.w);
  o[4] = f2b(b.x); o[5] = f2b(b.y); o[6] = f2b(b.z); o[7] = f2b(b.w);
  *(bf16x8*)(dst + i) = o;
}

// ------------------------------------------------- m97-style 128x128x32 mainloop
__device__ __forceinline__ void gemm_tile_mainloop(
    const bf16* __restrict__ A, const bf16* __restrict__ Bw, int K,
    int rowBase, int colBase, bf16* lA, bf16* lB, f32x4 acc[4][4]) {
  const int t = threadIdx.x;
  const int w = t >> 6, lane = t & 63;
  const int lm = lane & 15, quad = lane >> 4;
  const int wr = (w >> 1) * 64, wc = (w & 1) * 64;

  for (int kt = 0; kt < K; kt += 32) {
#pragma unroll
    for (int i = 0; i < 2; i++) {
      const int c = i * 256 + t;
      const int r = c >> 2, cc = (c & 3) << 3;
      async16(A + (size_t)(rowBase + r) * K + (kt + cc), lA + (i * 256 + w * 64) * 8);
      async16(Bw + (size_t)(colBase + r) * K + (kt + cc), lB + (i * 256 + w * 64) * 8);
    }
    asm volatile("s_waitcnt vmcnt(0)" ::: "memory");
    __syncthreads();
    bf16x8 af[4], bfr[4];
#pragma unroll
    for (int f = 0; f < 4; f++)
      af[f] = *(const bf16x8*)(lA + (wr + f * 16 + lm) * 32 + quad * 8);
#pragma unroll
    for (int f = 0; f < 4; f++)
      bfr[f] = *(const bf16x8*)(lB + (wc + f * 16 + lm) * 32 + quad * 8);
#pragma unroll
    for (int fr = 0; fr < 4; fr++)
#pragma unroll
      for (int fc = 0; fc < 4; fc++)
        acc[fr][fc] = __builtin_amdgcn_mfma_f32_16x16x32_bf16(af[fr], bfr[fc], acc[fr][fc], 0, 0, 0);
    __syncthreads();
  }
}

// QKV projection: Q,K -> [B,H,S,Dh]; V -> TRANSPOSED [B,H,Dh,S]
__global__ __launch_bounds__(256) void gemm_qkv(const bf16* __restrict__ X,
                                                const bf16* __restrict__ W,
                                                bf16* __restrict__ Q,
                                                bf16* __restrict__ Kv,
                                                bf16* __restrict__ VT) {
  __shared__ __align__(16) bf16 lA[128 * 32];
  __shared__ __align__(16) bf16 lB[128 * 32];
  f32x4 acc[4][4];
  f32x4 z = {0.f, 0.f, 0.f, 0.f};
#pragma unroll
  for (int i = 0; i < 4; i++)
#pragma unroll
    for (int j = 0; j < 4; j++) acc[i][j] = z;

  const int rowBase = blockIdx.y * 128, colBase = blockIdx.x * 128;
  gemm_tile_mainloop(X, W, DIM, rowBase, colBase, lA, lB, acc);

  const int t = threadIdx.x, w = t >> 6, lane = t & 63;
  const int lm = lane & 15, quad = lane >> 4;
  const int wr = (w >> 1) * 64, wc = (w & 1) * 64;
  const int which = colBase >> 11;  // 0=Q 1=K 2=V
  if (which < 2) {
    bf16* dst = which ? Kv : Q;
#pragma unroll
    for (int fr = 0; fr < 4; fr++)
#pragma unroll
      for (int fc = 0; fc < 4; fc++)
#pragma unroll
        for (int r = 0; r < 4; r++) {
          int m = rowBase + wr + fr * 16 + quad * 4 + r;
          int n = (colBase + wc + fc * 16 + lm) & 2047;
          int h = n >> 7, d = n & 127;
          int b = m >> 11, s = m & 2047;
          dst[(((size_t)(b * N_HEADS + h) * SEQ) + s) * HEAD_DIM + d] = f2b(acc[fr][fc][r]);
        }
  } else {
#pragma unroll
    for (int fr = 0; fr < 4; fr++)
#pragma unroll
      for (int fc = 0; fc < 4; fc++) {
        int n = (colBase + wc + fc * 16 + lm) & 2047;
        int h = n >> 7, d = n & 127;
        int m = rowBase + wr + fr * 16 + quad * 4;
        int b = m >> 11, s = m & 2047;
        bf16x4 pk;
#pragma unroll
        for (int r = 0; r < 4; r++) pk[r] = f2b(acc[fr][fc][r]);
        *(bf16x4*)&VT[((size_t)(b * N_HEADS + h) * HEAD_DIM + d) * SEQ + s] = pk;
      }
  }
}

// Output projection
__global__ __launch_bounds__(256) void gemm_out(const bf16* __restrict__ A,
                                                const bf16* __restrict__ W,
                                                float* __restrict__ out) {
  __shared__ __align__(16) bf16 lA[128 * 32];
  __shared__ __align__(16) bf16 lB[128 * 32];
  f32x4 acc[4][4];
  f32x4 z = {0.f, 0.f, 0.f, 0.f};
#pragma unroll
  for (int i = 0; i < 4; i++)
#pragma unroll
    for (int j = 0; j < 4; j++) acc[i][j] = z;

  const int rowBase = blockIdx.y * 128, colBase = blockIdx.x * 128;
  gemm_tile_mainloop(A, W, DIM, rowBase, colBase, lA, lB, acc);

  const int t = threadIdx.x, w = t >> 6, lane = t & 63;
  const int lm = lane & 15, quad = lane >> 4;
  const int wr = (w >> 1) * 64, wc = (w & 1) * 64;
#pragma unroll
  for (int fr = 0; fr < 4; fr++)
#pragma unroll
    for (int fc = 0; fc < 4; fc++)
#pragma unroll
      for (int r = 0; r < 4; r++) {
        int m = rowBase + wr + fr * 16 + quad * 4 + r;
        int n = colBase + wc + fc * 16 + lm;
        out[(size_t)m * DIM + n] = acc[fr][fc][r];
      }
}

// --------------------------------------------- RMSNorm + RoPE (in place on q,k)
// Q additionally pre-scaled by SM_SCALE*log2(e) so attn softmax runs in exp2
// domain (bare v_exp_f32, no per-element mul).
__global__ __launch_bounds__(256) void norm_rope(bf16* __restrict__ Q,
                                                 bf16* __restrict__ K,
                                                 const float* __restrict__ rope,
                                                 const float* __restrict__ qw,
                                                 const float* __restrict__ kw) {
  const int t = threadIdx.x, w = t >> 6, lane = t & 63;
  const int rid = blockIdx.x * 4 + w;
  const int which = rid >> 16;          // 0 = q, 1 = k
  const int row = rid & 65535;          // (b*16+h)*2048 + s
  bf16* ptr = (which ? K : Q) + (size_t)row * HEAD_DIM;
  const float* nw = which ? kw : qw;
  const int s = row & (SEQ - 1);

  float x0 = (float)ptr[lane];
  float x1 = (float)ptr[lane + 64];
  float ss = x0 * x0 + x1 * x1;
#pragma unroll
  for (int off = 32; off; off >>= 1) ss += __shfl_xor(ss, off);
  float r = rsqrtf(ss * (1.f / 128.f) + 1e-6f);
  float x0n = x0 * r * nw[lane];
  float x1n = x1 * r * nw[lane + 64];
  float4 f = ((const float4*)rope)[s * 64 + lane];
  float y0 = f.x * x0n + f.y * x1n;
  float y1 = f.z * x0n + f.w * x1n;
  if (!which) { y0 *= QSCALE_L2E; y1 *= QSCALE_L2E; }
  ptr[lane] = f2b(y0);
  ptr[lane + 64] = f2b(y1);
}

// --------------------------------------------------------- flash attention v8
// EXACT v5 structure (R0, 150.6 us measured): grid (bh=32, qt=16), bh%8 pins
// all q-tile blocks of a (b,h) to one XCD; 4 waves = (qh, kb); Br=128, Bc=64.
// Staging: coalesced global b128 -> VGPR (issued one full compute phase
// ahead) -> swizzled ds_write; TWO barriers per tile. R1/R2 post-mortems:
// (1) direct-from-L2 frag loads latency-serialize at 2 waves/SIMD;
// (2) dbuf/1-barrier/setprio destroys cross-block L2 lockstep (FETCH 34->585
// MB). The v5 barrier cadence is load-bearing — DO NOT perturb.
// v8 = v5 + softmax-phase-only micro-opts (no address/sync/timing change):
//   - exp2-domain softmax (Q pre-scaled by log2e upstream; bias -SMAX*log2e)
//   - 4-way partial rsum (breaks the 32-deep dependent add chain)
__global__ __launch_bounds__(256, 2) void attn_kernel(const bf16* __restrict__ Q,
                                                      const bf16* __restrict__ K,
                                                      const bf16* __restrict__ VT,
                                                      bf16* __restrict__ O) {
  __shared__ __align__(16) bf16 Ks[64 * 128];   // [kr][chunk ^ (kr&15)]
  __shared__ __align__(16) bf16 Vs[128 * 64];   // [d][chunk ^ (d&7)]

  const int t = threadIdx.x, w = t >> 6, lane = t & 63;
  const int lq = lane & 31, h = lane >> 5;
  const int qh = w >> 1, kb = w & 1;
  const int bh = blockIdx.x, qt = blockIdx.y;

  // hoisted Q B-frags, 2 q-sets of 32 rows
  bf16x8 qf[2][8];
#pragma unroll
  for (int qs = 0; qs < 2; qs++) {
    const bf16* Qp = Q + ((size_t)bh * SEQ + qt * 128 + qh * 64 + qs * 32 + lq) * HEAD_DIM;
#pragma unroll
    for (int ks = 0; ks < 8; ks++)
      qf[qs][ks] = *(const bf16x8*)(Qp + ks * 16 + h * 8);
  }

  f32x16 oacc[2][4];
#pragma unroll
  for (int qs = 0; qs < 2; qs++)
#pragma unroll
    for (int nb = 0; nb < 4; nb++)
#pragma unroll
      for (int e = 0; e < 16; e++) oacc[qs][nb][e] = 0.f;
  float rsum[2] = {0.f, 0.f};

  const bf16* kbase = K + (size_t)bh * SEQ * HEAD_DIM;
  const bf16* vbase = VT + (size_t)bh * HEAD_DIM * SEQ;
  const int kr = kb * 32 + lq;

  // staging registers + index helpers (per wave: 16 K-rows, 32 V-rows)
  const int krow = w * 16 + (lane >> 4), kcc = lane & 15;        // K: 4 rows/instr
  const int vrow = w * 32 + (lane >> 3), vcc = lane & 7;         // V: 8 rows/instr
  bf16x8 kreg[4], vreg[4];

  auto load_tile = [&](int j) {
    const bf16* kp = kbase + (size_t)j * 64 * HEAD_DIM;
    const bf16* vp = vbase + j * 64;
#pragma unroll
    for (int i = 0; i < 4; i++)
      kreg[i] = *(const bf16x8*)(kp + (krow + i * 4) * HEAD_DIM + kcc * 8);
#pragma unroll
    for (int i = 0; i < 4; i++)
      vreg[i] = *(const bf16x8*)(vp + (size_t)(vrow + i * 8) * SEQ + vcc * 8);
  };

  load_tile(0);

  for (int j = 0; j < SEQ / 64; j++) {
    // phase A: write staged regs (tile j) into swizzled LDS
#pragma unroll
    for (int i = 0; i < 4; i++) {
      int r = krow + i * 4;
      *(bf16x8*)&Ks[r * 128 + ((kcc ^ (r & 15)) << 3)] = kreg[i];
    }
#pragma unroll
    for (int i = 0; i < 4; i++) {
      int d = vrow + i * 8;
      *(bf16x8*)&Vs[d * 64 + ((vcc ^ (d & 7)) << 3)] = vreg[i];
    }
    __syncthreads();

    // phase B: issue next tile's global loads, then compute on LDS tile j
    if (j + 1 < SEQ / 64) load_tile(j + 1);

    // S^T = K Q^T on this wave's 32-row K-band; each kf feeds both q-sets
    f32x16 sacc[2];
#pragma unroll
    for (int qs = 0; qs < 2; qs++)
#pragma unroll
      for (int e = 0; e < 16; e++) sacc[qs][e] = -SMAX_L2E;  // p = exp2(sacc)
#pragma unroll
    for (int ks = 0; ks < 8; ks++) {
      int c = ks * 2 + h;
      bf16x8 kf = *(const bf16x8*)&Ks[kr * 128 + ((c ^ (kr & 15)) << 3)];
      sacc[0] = __builtin_amdgcn_mfma_f32_32x32x16_bf16(kf, qf[0][ks], sacc[0], 0, 0, 0);
      sacc[1] = __builtin_amdgcn_mfma_f32_32x32x16_bf16(kf, qf[1][ks], sacc[1], 0, 0, 0);
    }

    // exp2 + pack + in-register C->A transform (cross-half shfl_xor)
    uint32_t a1[2][4], a2[2][4];
#pragma unroll
    for (int qs = 0; qs < 2; qs++) {
      float e[16];
      float p0 = 0.f, p1 = 0.f, p2 = 0.f, p3 = 0.f;
#pragma unroll
      for (int r = 0; r < 16; r += 4) {
        e[r]     = __builtin_amdgcn_exp2f(sacc[qs][r]);
        e[r + 1] = __builtin_amdgcn_exp2f(sacc[qs][r + 1]);
        e[r + 2] = __builtin_amdgcn_exp2f(sacc[qs][r + 2]);
        e[r + 3] = __builtin_amdgcn_exp2f(sacc[qs][r + 3]);
        p0 += e[r]; p1 += e[r + 1]; p2 += e[r + 2]; p3 += e[r + 3];
      }
      rsum[qs] += (p0 + p1) + (p2 + p3);
      uint32_t pk[8];
#pragma unroll
      for (int i = 0; i < 8; i++) pk[i] = pack2(e[2 * i], e[2 * i + 1]);
      uint32_t ta = h ? pk[0] : pk[2], tb = h ? pk[1] : pk[3];
      uint32_t tc = h ? pk[4] : pk[6], td = h ? pk[5] : pk[7];
      uint32_t ra = __shfl_xor((int)ta, 32), rb = __shfl_xor((int)tb, 32);
      uint32_t rc = __shfl_xor((int)tc, 32), rd = __shfl_xor((int)td, 32);
      a1[qs][0] = h ? ra : pk[0]; a1[qs][1] = h ? rb : pk[1];
      a1[qs][2] = h ? pk[2] : ra; a1[qs][3] = h ? pk[3] : rb;
      a2[qs][0] = h ? rc : pk[4]; a2[qs][1] = h ? rd : pk[5];
      a2[qs][2] = h ? pk[6] : rc; a2[qs][3] = h ? pk[7] : rd;
    }

    // O += P V on this wave's K-band; each bv feeds both q-sets
#pragma unroll
    for (int ks2 = 0; ks2 < 2; ks2++) {
      union { uint32_t u[4]; bf16x8 v; } ap0, ap1;
#pragma unroll
      for (int i = 0; i < 4; i++) {
        ap0.u[i] = ks2 ? a2[0][i] : a1[0][i];
        ap1.u[i] = ks2 ? a2[1][i] : a1[1][i];
      }
      int c2 = kb * 4 + ks2 * 2 + h;
#pragma unroll
      for (int nb = 0; nb < 4; nb++) {
        int rv = nb * 32 + lq;
        bf16x8 bv = *(const bf16x8*)&Vs[rv * 64 + ((c2 ^ (rv & 7)) << 3)];
        oacc[0][nb] = __builtin_amdgcn_mfma_f32_32x32x16_bf16(ap0.v, bv, oacc[0][nb], 0, 0, 0);
        oacc[1][nb] = __builtin_amdgcn_mfma_f32_32x32x16_bf16(ap1.v, bv, oacc[1][nb], 0, 0, 0);
      }
    }
    __syncthreads();   // all waves done reading LDS tile j before next ds_write
  }

  // ---- epilogue: merge kb pairs via LDS (alias Ks/Vs), normalize, store
  rsum[0] += __shfl_xor(rsum[0], 32);
  rsum[1] += __shfl_xor(rsum[1], 32);
  float* Om = (float*)&Ks[0];   // [pair][64 q][32 d] f32 = 16 KB
  float* Rs = (float*)&Vs[0];   // [pair][qs][32] f32
  const int pair = qh;
  const int b = bh >> 4, hh = bh & 15;
  float inv[2] = {0.f, 0.f};

#pragma unroll
  for (int nb = 0; nb < 4; nb++) {
    if (kb == 1) {
      if (nb == 0 && h == 0) {
        Rs[(pair * 2 + 0) * 32 + lq] = rsum[0];
        Rs[(pair * 2 + 1) * 32 + lq] = rsum[1];
      }
#pragma unroll
      for (int qs = 0; qs < 2; qs++)
#pragma unroll
        for (int r = 0; r < 16; r++) {
          int rowm = (r & 3) + 8 * (r >> 2) + 4 * h;
          Om[(pair * 64 + qs * 32 + rowm) * 32 + lq] = oacc[qs][nb][r];
        }
    }
    __syncthreads();
    if (kb == 0) {
      if (nb == 0) {
        inv[0] = 1.f / (rsum[0] + Rs[(pair * 2 + 0) * 32 + lq]);
        inv[1] = 1.f / (rsum[1] + Rs[(pair * 2 + 1) * 32 + lq]);
      }
#pragma unroll
      for (int qs = 0; qs < 2; qs++)
#pragma unroll
        for (int r = 0; r < 16; r++) {
          int rowm = (r & 3) + 8 * (r >> 2) + 4 * h;
          float val = oacc[qs][nb][r] + Om[(pair * 64 + qs * 32 + rowm) * 32 + lq];
          float iv = __shfl(inv[qs], rowm);
          int qg = qt * 128 + qh * 64 + qs * 32 + rowm;
          O[((size_t)b * SEQ + qg) * DIM + hh * HEAD_DIM + nb * 32 + lq] = f2b(val * iv);
        }
    }
    __syncthreads();
  }
}

extern "C" void kernel_launch(void* const* d_in, const int* in_sizes, int n_in,
                              void* d_out, int out_size, void* d_ws, size_t ws_size,
                              hipStream_t stream) {
  const float* x    = (const float*)d_in[0];
  const float* rope = (const float*)d_in[1];
  const float* Wq   = (const float*)d_in[2];
  const float* Wk   = (const float*)d_in[3];
  const float* Wv   = (const float*)d_in[4];
  const float* Wo   = (const float*)d_in[5];
  const float* qw   = (const float*)d_in[6];
  const float* kw   = (const float*)d_in[7];
  float* out = (float*)d_out;

  char* ws = (char*)d_ws;
  bf16* xb   = (bf16*)ws;                        // 16 MB; reused as attn-out
  bf16* wqkv = (bf16*)(ws + (16u << 20));        // 24 MB
  bf16* wo   = (bf16*)(ws + (40u << 20));        // 8 MB
  bf16* qb   = (bf16*)(ws + (48u << 20));        // 16 MB [B,H,S,Dh]
  bf16* kb   = (bf16*)(ws + (64u << 20));        // 16 MB [B,H,S,Dh]
  bf16* vt   = (bf16*)(ws + (80u << 20));        // 16 MB [B,H,Dh,S]
  bf16* attn = xb;

  const int NX = MROWS * DIM;
  const int NW = DIM * DIM;

  cvt_kernel<<<NX / 8 / 256, 256, 0, stream>>>(x, xb, NX);
  cvt_w4<<<4 * (NW / 8 / 256), 256, 0, stream>>>(Wq, Wk, Wv, Wo, wqkv, wo);

  gemm_qkv<<<dim3(NQKV / 128, MROWS / 128), 256, 0, stream>>>(xb, wqkv, qb, kb, vt);
  norm_rope<<<(2 * BATCH * N_HEADS * SEQ) / 4, 256, 0, stream>>>(qb, kb, rope, qw, kw);
  attn_kernel<<<dim3(BATCH * N_HEADS, SEQ / 128), 256, 0, stream>>>(qb, kb, vt, attn);
  gemm_out<<<dim3(DIM / 128, MROWS / 128), 256, 0, stream>>>(attn, wo, out);
}

// Round 4
// 417.657 us; speedup vs baseline: 1.4453x; 1.1119x over previous
//
#include <hip/hip_runtime.h>
#include <hip/hip_bf16.h>
#include <stdint.h>

typedef __bf16 bf16;
typedef __bf16 bf16x4 __attribute__((ext_vector_type(4)));
typedef __bf16 bf16x8 __attribute__((ext_vector_type(8)));
typedef float f32x4 __attribute__((ext_vector_type(4)));
typedef float f32x16 __attribute__((ext_vector_type(16)));

#define N_HEADS 16
#define HEAD_DIM 128
#define SEQ 2048
#define DIM 2048
#define BATCH 2
#define MROWS (BATCH * SEQ)          // 4096
#define NQKV (3 * DIM)               // 6144
#define SM_SCALE 0.08838834764831845f   // 1/sqrt(128)
// exp2-domain softmax: Q pre-scaled by SM_SCALE*log2(e); bias = SMAX*log2(e)
#define QSCALE_L2E 0.12751743343563824f // SM_SCALE * 1.4426950408889634
#define SMAX_L2E 34.624680981335122f    // 24.0 * log2(e)

__device__ __forceinline__ bf16 f2b(float f) {
  union { __hip_bfloat16 h; bf16 b; } u;
  u.h = __float2bfloat16(f);
  return u.b;
}

__device__ __forceinline__ uint32_t pack2(float a, float b) {
  union { __hip_bfloat16 h; unsigned short s; } ua, ub;
  ua.h = __float2bfloat16(a); ub.h = __float2bfloat16(b);
  return (uint32_t)ua.s | ((uint32_t)ub.s << 16);   // a in low 16 (even k)
}

// async global->LDS (GEMMs only; lane-contiguous source, the m97 pattern)
__device__ __forceinline__ void async16(const bf16* g, bf16* l) {
  __builtin_amdgcn_global_load_lds(
      (__attribute__((address_space(1))) void*)(uintptr_t)g,
      (__attribute__((address_space(3))) void*)(uintptr_t)l,
      16, 0, 0);
}

// ---------------------------------------------------------------- cvt f32->bf16
__global__ __launch_bounds__(256) void cvt_kernel(const float* __restrict__ src,
                                                  bf16* __restrict__ dst, int n) {
  int i = (blockIdx.x * 256 + threadIdx.x) * 8;
  if (i >= n) return;
  float4 a = *(const float4*)(src + i);
  float4 b = *(const float4*)(src + i + 4);
  bf16x8 o;
  o[0] = f2b(a.x); o[1] = f2b(a.y); o[2] = f2b(a.z); o[3] = f2b(a.w);
  o[4] = f2b(b.x); o[5] = f2b(b.y); o[6] = f2b(b.z); o[7] = f2b(b.w);
  *(bf16x8*)(dst + i) = o;
}

// fused cvt of the 4 weight matrices; w0..w2 -> wqkv, w3 -> wo
__global__ __launch_bounds__(256) void cvt_w4(const float* __restrict__ w0,
                                              const float* __restrict__ w1,
                                              const float* __restrict__ w2,
                                              const float* __restrict__ w3,
                                              bf16* __restrict__ wqkv,
                                              bf16* __restrict__ wo) {
  const int per = (DIM * DIM) / 8 / 256;
  int which = blockIdx.x / per;
  int i = (blockIdx.x % per) * 256 * 8 + threadIdx.x * 8;
  const float* src = which == 0 ? w0 : which == 1 ? w1 : which == 2 ? w2 : w3;
  bf16* dst = which < 3 ? wqkv + (size_t)which * DIM * DIM : wo;
  float4 a = *(const float4*)(src + i);
  float4 b = *(const float4*)(src + i + 4);
  bf16x8 o;
  o[0] = f2b(a.x); o[1] = f2b(a.y); o[2] = f2b(a.z); o[3] = f2b(a.w);
  o[4] = f2b(b.x); o[5] = f2b(b.y); o[6] = f2b(b.z); o[7] = f2b(b.w);
  *(bf16x8*)(dst + i) = o;
}

// ------------------------------------------------- m97-style 128x128x32 mainloop
__device__ __forceinline__ void gemm_tile_mainloop(
    const bf16* __restrict__ A, const bf16* __restrict__ Bw, int K,
    int rowBase, int colBase, bf16* lA, bf16* lB, f32x4 acc[4][4]) {
  const int t = threadIdx.x;
  const int w = t >> 6, lane = t & 63;
  const int lm = lane & 15, quad = lane >> 4;
  const int wr = (w >> 1) * 64, wc = (w & 1) * 64;

  for (int kt = 0; kt < K; kt += 32) {
#pragma unroll
    for (int i = 0; i < 2; i++) {
      const int c = i * 256 + t;
      const int r = c >> 2, cc = (c & 3) << 3;
      async16(A + (size_t)(rowBase + r) * K + (kt + cc), lA + (i * 256 + w * 64) * 8);
      async16(Bw + (size_t)(colBase + r) * K + (kt + cc), lB + (i * 256 + w * 64) * 8);
    }
    asm volatile("s_waitcnt vmcnt(0)" ::: "memory");
    __syncthreads();
    bf16x8 af[4], bfr[4];
#pragma unroll
    for (int f = 0; f < 4; f++)
      af[f] = *(const bf16x8*)(lA + (wr + f * 16 + lm) * 32 + quad * 8);
#pragma unroll
    for (int f = 0; f < 4; f++)
      bfr[f] = *(const bf16x8*)(lB + (wc + f * 16 + lm) * 32 + quad * 8);
#pragma unroll
    for (int fr = 0; fr < 4; fr++)
#pragma unroll
      for (int fc = 0; fc < 4; fc++)
        acc[fr][fc] = __builtin_amdgcn_mfma_f32_16x16x32_bf16(af[fr], bfr[fc], acc[fr][fc], 0, 0, 0);
    __syncthreads();
  }
}

// QKV projection: Q,K -> [B,H,S,Dh]; V -> TRANSPOSED [B,H,Dh,S]
__global__ __launch_bounds__(256) void gemm_qkv(const bf16* __restrict__ X,
                                                const bf16* __restrict__ W,
                                                bf16* __restrict__ Q,
                                                bf16* __restrict__ Kv,
                                                bf16* __restrict__ VT) {
  __shared__ __align__(16) bf16 lA[128 * 32];
  __shared__ __align__(16) bf16 lB[128 * 32];
  f32x4 acc[4][4];
  f32x4 z = {0.f, 0.f, 0.f, 0.f};
#pragma unroll
  for (int i = 0; i < 4; i++)
#pragma unroll
    for (int j = 0; j < 4; j++) acc[i][j] = z;

  const int rowBase = blockIdx.y * 128, colBase = blockIdx.x * 128;
  gemm_tile_mainloop(X, W, DIM, rowBase, colBase, lA, lB, acc);

  const int t = threadIdx.x, w = t >> 6, lane = t & 63;
  const int lm = lane & 15, quad = lane >> 4;
  const int wr = (w >> 1) * 64, wc = (w & 1) * 64;
  const int which = colBase >> 11;  // 0=Q 1=K 2=V
  if (which < 2) {
    bf16* dst = which ? Kv : Q;
#pragma unroll
    for (int fr = 0; fr < 4; fr++)
#pragma unroll
      for (int fc = 0; fc < 4; fc++)
#pragma unroll
        for (int r = 0; r < 4; r++) {
          int m = rowBase + wr + fr * 16 + quad * 4 + r;
          int n = (colBase + wc + fc * 16 + lm) & 2047;
          int h = n >> 7, d = n & 127;
          int b = m >> 11, s = m & 2047;
          dst[(((size_t)(b * N_HEADS + h) * SEQ) + s) * HEAD_DIM + d] = f2b(acc[fr][fc][r]);
        }
  } else {
#pragma unroll
    for (int fr = 0; fr < 4; fr++)
#pragma unroll
      for (int fc = 0; fc < 4; fc++) {
        int n = (colBase + wc + fc * 16 + lm) & 2047;
        int h = n >> 7, d = n & 127;
        int m = rowBase + wr + fr * 16 + quad * 4;
        int b = m >> 11, s = m & 2047;
        bf16x4 pk;
#pragma unroll
        for (int r = 0; r < 4; r++) pk[r] = f2b(acc[fr][fc][r]);
        *(bf16x4*)&VT[((size_t)(b * N_HEADS + h) * HEAD_DIM + d) * SEQ + s] = pk;
      }
  }
}

// Output projection
__global__ __launch_bounds__(256) void gemm_out(const bf16* __restrict__ A,
                                                const bf16* __restrict__ W,
                                                float* __restrict__ out) {
  __shared__ __align__(16) bf16 lA[128 * 32];
  __shared__ __align__(16) bf16 lB[128 * 32];
  f32x4 acc[4][4];
  f32x4 z = {0.f, 0.f, 0.f, 0.f};
#pragma unroll
  for (int i = 0; i < 4; i++)
#pragma unroll
    for (int j = 0; j < 4; j++) acc[i][j] = z;

  const int rowBase = blockIdx.y * 128, colBase = blockIdx.x * 128;
  gemm_tile_mainloop(A, W, DIM, rowBase, colBase, lA, lB, acc);

  const int t = threadIdx.x, w = t >> 6, lane = t & 63;
  const int lm = lane & 15, quad = lane >> 4;
  const int wr = (w >> 1) * 64, wc = (w & 1) * 64;
#pragma unroll
  for (int fr = 0; fr < 4; fr++)
#pragma unroll
    for (int fc = 0; fc < 4; fc++)
#pragma unroll
      for (int r = 0; r < 4; r++) {
        int m = rowBase + wr + fr * 16 + quad * 4 + r;
        int n = colBase + wc + fc * 16 + lm;
        out[(size_t)m * DIM + n] = acc[fr][fc][r];
      }
}

// --------------------------------------------- RMSNorm + RoPE (in place on q,k)
// Q additionally pre-scaled by SM_SCALE*log2(e) so attn softmax runs in exp2
// domain (bare v_exp_f32, no per-element mul).
__global__ __launch_bounds__(256) void norm_rope(bf16* __restrict__ Q,
                                                 bf16* __restrict__ K,
                                                 const float* __restrict__ rope,
                                                 const float* __restrict__ qw,
                                                 const float* __restrict__ kw) {
  const int t = threadIdx.x, w = t >> 6, lane = t & 63;
  const int rid = blockIdx.x * 4 + w;
  const int which = rid >> 16;          // 0 = q, 1 = k
  const int row = rid & 65535;          // (b*16+h)*2048 + s
  bf16* ptr = (which ? K : Q) + (size_t)row * HEAD_DIM;
  const float* nw = which ? kw : qw;
  const int s = row & (SEQ - 1);

  float x0 = (float)ptr[lane];
  float x1 = (float)ptr[lane + 64];
  float ss = x0 * x0 + x1 * x1;
#pragma unroll
  for (int off = 32; off; off >>= 1) ss += __shfl_xor(ss, off);
  float r = rsqrtf(ss * (1.f / 128.f) + 1e-6f);
  float x0n = x0 * r * nw[lane];
  float x1n = x1 * r * nw[lane + 64];
  float4 f = ((const float4*)rope)[s * 64 + lane];
  float y0 = f.x * x0n + f.y * x1n;
  float y1 = f.z * x0n + f.w * x1n;
  if (!which) { y0 *= QSCALE_L2E; y1 *= QSCALE_L2E; }
  ptr[lane] = f2b(y0);
  ptr[lane + 64] = f2b(y1);
}

// --------------------------------------------------------- flash attention v9
// R3 post-mortem arithmetic: all 512 blocks co-resident -> 11.1Kcy per
// kv-tile per wave, of which only ~1Kcy is work. The stall is the per-tile
// sync quantum (2 barriers + staging issue per 64 keys). v9 doubles the
// work quantum per sync: Bc 64->128 (2 barriers per 128 keys), and
// re-partitions waves: each of the 4 waves owns 32 q-rows x ALL 128 keys
// (no kb-split, no qs-split). This keeps the proven v5 cadence (2 barriers
// per tile, reg-staged prefetch issued a full compute phase ahead, same
// grid/XCD pinning, 2 blocks/CU) while halving per-key sync+staging-issue
// cost and ELIMINATING the LDS epilogue merge (waves own complete rows).
// All fragment formulas are the v5-verified isomorphism with `band` (0..3,
// 32-key groups) playing kb's role: c = ks*2+h, c2 = band*4+ks2*2+h, same
// C->A shfl_xor(32) transform verbatim.
__global__ __launch_bounds__(256, 2) void attn_kernel(const bf16* __restrict__ Q,
                                                      const bf16* __restrict__ K,
                                                      const bf16* __restrict__ VT,
                                                      bf16* __restrict__ O) {
  __shared__ __align__(16) bf16 Ks[128 * 128];   // [k-row][d-chunk ^ (row&15)]
  __shared__ __align__(16) bf16 Vs[128 * 128];   // [d-row][k-chunk ^ (row&15)]

  const int t = threadIdx.x, w = t >> 6, lane = t & 63;
  const int lq = lane & 31, h = lane >> 5;
  const int bh = blockIdx.x, qt = blockIdx.y;

  // Q B-frags: wave w owns q-rows qt*128 + w*32 + lq
  bf16x8 qf[8];
  {
    const bf16* Qp = Q + ((size_t)bh * SEQ + qt * 128 + w * 32 + lq) * HEAD_DIM;
#pragma unroll
    for (int ks = 0; ks < 8; ks++)
      qf[ks] = *(const bf16x8*)(Qp + ks * 16 + h * 8);
  }

  f32x16 oacc[4];
#pragma unroll
  for (int nb = 0; nb < 4; nb++)
#pragma unroll
    for (int e = 0; e < 16; e++) oacc[nb][e] = 0.f;
  float rsum = 0.f;

  const bf16* kbase = K + (size_t)bh * SEQ * HEAD_DIM;
  const bf16* vbase = VT + (size_t)bh * HEAD_DIM * SEQ;

  // staging: per wave 32 K-rows + 32 V-rows; instr covers 4 rows x 16 chunks
  const int srow = w * 32 + (lane >> 4), scc = lane & 15;
  bf16x8 kreg[8], vreg[8];

  auto load_tile = [&](int j) {
    const bf16* kp = kbase + (size_t)j * 128 * HEAD_DIM;
    const bf16* vp = vbase + j * 128;
#pragma unroll
    for (int i = 0; i < 8; i++)
      kreg[i] = *(const bf16x8*)(kp + (size_t)(srow + i * 4) * HEAD_DIM + scc * 8);
#pragma unroll
    for (int i = 0; i < 8; i++)
      vreg[i] = *(const bf16x8*)(vp + (size_t)(srow + i * 4) * SEQ + scc * 8);
  };

  load_tile(0);

  for (int j = 0; j < SEQ / 128; j++) {
    // phase A: write staged regs (tile j) into swizzled LDS
#pragma unroll
    for (int i = 0; i < 8; i++) {
      int r = srow + i * 4;
      *(bf16x8*)&Ks[r * 128 + ((scc ^ (r & 15)) << 3)] = kreg[i];
    }
#pragma unroll
    for (int i = 0; i < 8; i++) {
      int d = srow + i * 4;
      *(bf16x8*)&Vs[d * 128 + ((scc ^ (d & 15)) << 3)] = vreg[i];
    }
    __syncthreads();

    // phase B: issue next tile's global loads, then compute on LDS tile j
    if (j + 1 < SEQ / 128) load_tile(j + 1);

#pragma unroll
    for (int bp = 0; bp < 2; bp++) {   // band pairs: bands 2bp, 2bp+1
      // S^T = K Q^T for two 32-key bands (two interleaved MFMA chains)
      f32x16 sacc[2];
#pragma unroll
      for (int bb = 0; bb < 2; bb++)
#pragma unroll
        for (int e = 0; e < 16; e++) sacc[bb][e] = -SMAX_L2E;  // p = exp2(sacc)
      const int r0 = bp * 64 + lq, r1 = r0 + 32;
#pragma unroll
      for (int ks = 0; ks < 8; ks++) {
        int c = ks * 2 + h;
        bf16x8 kf0 = *(const bf16x8*)&Ks[r0 * 128 + ((c ^ (r0 & 15)) << 3)];
        bf16x8 kf1 = *(const bf16x8*)&Ks[r1 * 128 + ((c ^ (r1 & 15)) << 3)];
        sacc[0] = __builtin_amdgcn_mfma_f32_32x32x16_bf16(kf0, qf[ks], sacc[0], 0, 0, 0);
        sacc[1] = __builtin_amdgcn_mfma_f32_32x32x16_bf16(kf1, qf[ks], sacc[1], 0, 0, 0);
      }

      // exp2 + pack + in-register C->A transform (cross-half shfl_xor)
      uint32_t a1[2][4], a2[2][4];
#pragma unroll
      for (int bb = 0; bb < 2; bb++) {
        float e[16];
        float p0 = 0.f, p1 = 0.f, p2 = 0.f, p3 = 0.f;
#pragma unroll
        for (int r = 0; r < 16; r += 4) {
          e[r]     = __builtin_amdgcn_exp2f(sacc[bb][r]);
          e[r + 1] = __builtin_amdgcn_exp2f(sacc[bb][r + 1]);
          e[r + 2] = __builtin_amdgcn_exp2f(sacc[bb][r + 2]);
          e[r + 3] = __builtin_amdgcn_exp2f(sacc[bb][r + 3]);
          p0 += e[r]; p1 += e[r + 1]; p2 += e[r + 2]; p3 += e[r + 3];
        }
        rsum += (p0 + p1) + (p2 + p3);
        uint32_t pk[8];
#pragma unroll
        for (int i = 0; i < 8; i++) pk[i] = pack2(e[2 * i], e[2 * i + 1]);
        uint32_t ta = h ? pk[0] : pk[2], tb = h ? pk[1] : pk[3];
        uint32_t tc = h ? pk[4] : pk[6], td = h ? pk[5] : pk[7];
        uint32_t ra = __shfl_xor((int)ta, 32), rb = __shfl_xor((int)tb, 32);
        uint32_t rc = __shfl_xor((int)tc, 32), rd = __shfl_xor((int)td, 32);
        a1[bb][0] = h ? ra : pk[0]; a1[bb][1] = h ? rb : pk[1];
        a1[bb][2] = h ? pk[2] : ra; a1[bb][3] = h ? pk[3] : rb;
        a2[bb][0] = h ? rc : pk[4]; a2[bb][1] = h ? rd : pk[5];
        a2[bb][2] = h ? pk[6] : rc; a2[bb][3] = h ? pk[7] : rd;
      }

      // O += P V over this band pair
#pragma unroll
      for (int bb = 0; bb < 2; bb++)
#pragma unroll
        for (int ks2 = 0; ks2 < 2; ks2++) {
          union { uint32_t u[4]; bf16x8 v; } ap;
#pragma unroll
          for (int i = 0; i < 4; i++) ap.u[i] = ks2 ? a2[bb][i] : a1[bb][i];
          int c2 = (bp * 2 + bb) * 4 + ks2 * 2 + h;
#pragma unroll
          for (int nb = 0; nb < 4; nb++) {
            int rv = nb * 32 + lq;
            bf16x8 bv = *(const bf16x8*)&Vs[rv * 128 + ((c2 ^ (rv & 15)) << 3)];
            oacc[nb] = __builtin_amdgcn_mfma_f32_32x32x16_bf16(ap.v, bv, oacc[nb], 0, 0, 0);
          }
        }
    }
    __syncthreads();   // all waves done reading LDS tile j before next ds_write
  }

  // ---- epilogue: waves own complete q-rows -> direct normalize + store
  rsum += __shfl_xor(rsum, 32);
  float inv = 1.f / rsum;            // lane lq holds q-row (w*32+lq)'s total
  const int b = bh >> 4, hh = bh & 15;
#pragma unroll
  for (int nb = 0; nb < 4; nb++)
#pragma unroll
    for (int r = 0; r < 16; r++) {
      int q = (r & 3) + 8 * (r >> 2) + 4 * h;
      float iv = __shfl(inv, q);
      int qg = qt * 128 + w * 32 + q;
      O[((size_t)b * SEQ + qg) * DIM + hh * HEAD_DIM + nb * 32 + lq] = f2b(oacc[nb][r] * iv);
    }
}

extern "C" void kernel_launch(void* const* d_in, const int* in_sizes, int n_in,
                              void* d_out, int out_size, void* d_ws, size_t ws_size,
                              hipStream_t stream) {
  const float* x    = (const float*)d_in[0];
  const float* rope = (const float*)d_in[1];
  const float* Wq   = (const float*)d_in[2];
  const float* Wk   = (const float*)d_in[3];
  const float* Wv   = (const float*)d_in[4];
  const float* Wo   = (const float*)d_in[5];
  const float* qw   = (const float*)d_in[6];
  const float* kw   = (const float*)d_in[7];
  float* out = (float*)d_out;

  char* ws = (char*)d_ws;
  bf16* xb   = (bf16*)ws;                        // 16 MB; reused as attn-out
  bf16* wqkv = (bf16*)(ws + (16u << 20));        // 24 MB
  bf16* wo   = (bf16*)(ws + (40u << 20));        // 8 MB
  bf16* qb   = (bf16*)(ws + (48u << 20));        // 16 MB [B,H,S,Dh]
  bf16* kb   = (bf16*)(ws + (64u << 20));        // 16 MB [B,H,S,Dh]
  bf16* vt   = (bf16*)(ws + (80u << 20));        // 16 MB [B,H,Dh,S]
  bf16* attn = xb;

  const int NX = MROWS * DIM;
  const int NW = DIM * DIM;

  cvt_kernel<<<NX / 8 / 256, 256, 0, stream>>>(x, xb, NX);
  cvt_w4<<<4 * (NW / 8 / 256), 256, 0, stream>>>(Wq, Wk, Wv, Wo, wqkv, wo);

  gemm_qkv<<<dim3(NQKV / 128, MROWS / 128), 256, 0, stream>>>(xb, wqkv, qb, kb, vt);
  norm_rope<<<(2 * BATCH * N_HEADS * SEQ) / 4, 256, 0, stream>>>(qb, kb, rope, qw, kw);
  attn_kernel<<<dim3(BATCH * N_HEADS, SEQ / 128), 256, 0, stream>>>(qb, kb, vt, attn);
  gemm_out<<<dim3(DIM / 128, MROWS / 128), 256, 0, stream>>>(attn, wo, out);
}

// Round 5
// 416.338 us; speedup vs baseline: 1.4499x; 1.0032x over previous
//
#include <hip/hip_runtime.h>
#include <hip/hip_bf16.h>
#include <stdint.h>

typedef __bf16 bf16;
typedef __bf16 bf16x4 __attribute__((ext_vector_type(4)));
typedef __bf16 bf16x8 __attribute__((ext_vector_type(8)));
typedef float f32x4 __attribute__((ext_vector_type(4)));
typedef float f32x16 __attribute__((ext_vector_type(16)));

#define N_HEADS 16
#define HEAD_DIM 128
#define SEQ 2048
#define DIM 2048
#define BATCH 2
#define MROWS (BATCH * SEQ)          // 4096
#define NQKV (3 * DIM)               // 6144
#define SM_SCALE 0.08838834764831845f   // 1/sqrt(128)
// exp2-domain softmax: Q pre-scaled by SM_SCALE*log2(e); bias = SMAX*log2(e)
#define QSCALE_L2E 0.12751743343563824f // SM_SCALE * 1.4426950408889634
#define SMAX_L2E 34.624680981335122f    // 24.0 * log2(e)

#define MFMA16(a, b, c) __builtin_amdgcn_mfma_f32_16x16x32_bf16(a, b, c, 0, 0, 0)

__device__ __forceinline__ bf16 f2b(float f) {
  union { __hip_bfloat16 h; bf16 b; } u;
  u.h = __float2bfloat16(f);
  return u.b;
}

__device__ __forceinline__ uint32_t pack2(float a, float b) {
  union { __hip_bfloat16 h; unsigned short s; } ua, ub;
  ua.h = __float2bfloat16(a); ub.h = __float2bfloat16(b);
  return (uint32_t)ua.s | ((uint32_t)ub.s << 16);   // a in low 16 (even k)
}

// async global->LDS (lane-contiguous LDS dest; per-lane global source)
__device__ __forceinline__ void async16(const bf16* g, bf16* l) {
  __builtin_amdgcn_global_load_lds(
      (__attribute__((address_space(1))) void*)(uintptr_t)g,
      (__attribute__((address_space(3))) void*)(uintptr_t)l,
      16, 0, 0);
}

// ---------------------------------------------------------------- cvt f32->bf16
__global__ __launch_bounds__(256) void cvt_kernel(const float* __restrict__ src,
                                                  bf16* __restrict__ dst, int n) {
  int i = (blockIdx.x * 256 + threadIdx.x) * 8;
  if (i >= n) return;
  float4 a = *(const float4*)(src + i);
  float4 b = *(const float4*)(src + i + 4);
  bf16x8 o;
  o[0] = f2b(a.x); o[1] = f2b(a.y); o[2] = f2b(a.z); o[3] = f2b(a.w);
  o[4] = f2b(b.x); o[5] = f2b(b.y); o[6] = f2b(b.z); o[7] = f2b(b.w);
  *(bf16x8*)(dst + i) = o;
}

// fused cvt of the 4 weight matrices; w0..w2 -> wqkv, w3 -> wo
__global__ __launch_bounds__(256) void cvt_w4(const float* __restrict__ w0,
                                              const float* __restrict__ w1,
                                              const float* __restrict__ w2,
                                              const float* __restrict__ w3,
                                              bf16* __restrict__ wqkv,
                                              bf16* __restrict__ wo) {
  const int per = (DIM * DIM) / 8 / 256;
  int which = blockIdx.x / per;
  int i = (blockIdx.x % per) * 256 * 8 + threadIdx.x * 8;
  const float* src = which == 0 ? w0 : which == 1 ? w1 : which == 2 ? w2 : w3;
  bf16* dst = which < 3 ? wqkv + (size_t)which * DIM * DIM : wo;
  float4 a = *(const float4*)(src + i);
  float4 b = *(const float4*)(src + i + 4);
  bf16x8 o;
  o[0] = f2b(a.x); o[1] = f2b(a.y); o[2] = f2b(a.z); o[3] = f2b(a.w);
  o[4] = f2b(b.x); o[5] = f2b(b.y); o[6] = f2b(b.z); o[7] = f2b(b.w);
  *(bf16x8*)(dst + i) = o;
}

// ============================== 256x256x64 8-phase GEMM (T2+T3+T4+T5) =========
// Plain-HIP port of the m201 template. 8 waves (2M x 4N); per-wave out 128x64;
// LDS = 2 dbuf x (A[256][64] + B[256][64]) bf16 = 128 KB. Staging via
// global_load_lds w16: LINEAR LDS dest + inverse-swizzled global source
// (chunk ^= row&7, rule #21); ds_read applies the same XOR -> no 16-way
// stride-128B conflict (T2). Counted vmcnt(4) ONLY at phases 3/7 (T4);
// derivation: at p3, outstanding = {prev p6,p7, p0..p3} = 12 -> wait-to-4
// lands exactly tile t1's 4 halves before p4 reads. s_setprio around each
// 16-MFMA cluster (T5). End-of-K prefetches clamp to tile 31 and land only
// in barrier-certified-dead LDS regions.

#define GBAR() asm volatile("s_barrier" ::: "memory")
#define GWAITL() do { asm volatile("s_waitcnt lgkmcnt(0)" ::: "memory"); \
                      __builtin_amdgcn_sched_barrier(0); } while (0)

// stage one half (128 rows) of a [256][64]-bf16 tile for K-tile t.
// wave w covers rows [hf*128 + w*16, +16) as two 8-row / 1KB loads.
__device__ __forceinline__ void g256_stage_half(const bf16* gbase, bf16* lbase,
                                                int w, int lane, int t, int hf) {
  const int kt = t * 64;
#pragma unroll
  for (int i = 0; i < 2; i++) {
    const int rbase = hf * 128 + w * 16 + i * 8;
    const int r = rbase + (lane >> 3);
    async16(gbase + (size_t)r * 2048 + kt + 8 * ((lane & 7) ^ (r & 7)),
            lbase + rbase * 64);
  }
}

__device__ __forceinline__ void g256_lda(const bf16* lbase, int wm, int lm,
                                         int quad, int mh, bf16x8 a[4][2]) {
#pragma unroll
  for (int f = 0; f < 4; f++) {
    const int row = wm * 128 + mh * 64 + f * 16 + lm;
    const char* p = (const char*)lbase + row * 128;
    const int sw = (row & 7) << 4;
#pragma unroll
    for (int s = 0; s < 2; s++)
      a[f][s] = *(const bf16x8*)(p + ((s * 64 + quad * 16) ^ sw));
  }
}

__device__ __forceinline__ void g256_ldb(const bf16* lbase, int wn, int lm,
                                         int quad, int nh, bf16x8 bb[2][2]) {
#pragma unroll
  for (int g = 0; g < 2; g++) {
    const int row = wn * 64 + nh * 32 + g * 16 + lm;
    const char* p = (const char*)lbase + row * 128;
    const int sw = (row & 7) << 4;
#pragma unroll
    for (int s = 0; s < 2; s++)
      bb[g][s] = *(const bf16x8*)(p + ((s * 64 + quad * 16) ^ sw));
  }
}

__device__ __forceinline__ void g256_mma(f32x4 acc[8][4], bf16x8 a[4][2],
                                         bf16x8 bb[2][2], int mh, int nh) {
  __builtin_amdgcn_s_setprio(1);
#pragma unroll
  for (int s = 0; s < 2; s++)
#pragma unroll
    for (int f = 0; f < 4; f++)
#pragma unroll
      for (int g = 0; g < 2; g++)
        acc[mh * 4 + f][nh * 2 + g] =
            MFMA16(a[f][s], bb[g][s], acc[mh * 4 + f][nh * 2 + g]);
  __builtin_amdgcn_s_setprio(0);
}

__device__ __forceinline__ void gemm256_mainloop(
    const bf16* __restrict__ Ag, const bf16* __restrict__ Bg,
    bf16* sA0, bf16* sA1, bf16* sB0, bf16* sB1, f32x4 acc[8][4],
    int w, int lane, int wm, int wn, int lm, int quad) {
  // prologue: tile0 fully (buf0) + tile1 A-halves (buf1)
  g256_stage_half(Ag, sA0, w, lane, 0, 0);
  g256_stage_half(Ag, sA0, w, lane, 0, 1);
  g256_stage_half(Bg, sB0, w, lane, 0, 0);
  g256_stage_half(Bg, sB0, w, lane, 0, 1);
  g256_stage_half(Ag, sA1, w, lane, 1, 0);
  g256_stage_half(Ag, sA1, w, lane, 1, 1);
  asm volatile("s_waitcnt vmcnt(0)" ::: "memory");
  GBAR();

  bf16x8 a0[4][2], a1[4][2], bb[2][2];

  for (int i = 0; i < 16; i++) {
    const int t1 = 2 * i + 1;
    const int t2 = t1 + 1 < 32 ? t1 + 1 : 31;   // clamped prefetch tiles
    const int t3 = t1 + 2 < 32 ? t1 + 2 : 31;
    // ---------------- K-tile 2i in buf0 ----------------
    // p0: quad(0,0); read A0,B0(buf0); stage B0(t1)->buf1
    g256_lda(sA0, wm, lm, quad, 0, a0);
    g256_ldb(sB0, wn, lm, quad, 0, bb);
    g256_stage_half(Bg, sB1, w, lane, t1, 0);
    GBAR(); GWAITL();
    g256_mma(acc, a0, bb, 0, 0);
    GBAR();
    // p1: quad(1,0); read A1(buf0); stage B1(t1)->buf1
    g256_lda(sA0, wm, lm, quad, 1, a1);
    g256_stage_half(Bg, sB1, w, lane, t1, 1);
    GBAR(); GWAITL();
    g256_mma(acc, a1, bb, 1, 0);
    GBAR();
    // p2: quad(1,1); read B1(buf0); stage A0(t2)->buf0 (A dead after p1)
    g256_ldb(sB0, wn, lm, quad, 1, bb);
    g256_stage_half(Ag, sA0, w, lane, t2, 0);
    GBAR(); GWAITL();
    g256_mma(acc, a1, bb, 1, 1);
    GBAR();
    // p3: quad(0,1); stage A1(t2)->buf0; vmcnt(4) certifies tile t1 landed
    g256_stage_half(Ag, sA0, w, lane, t2, 1);
    asm volatile("s_waitcnt vmcnt(4)" ::: "memory");
    GBAR(); GWAITL();
    g256_mma(acc, a0, bb, 0, 1);
    GBAR();
    // ---------------- K-tile 2i+1 in buf1 ----------------
    // p4: quad(0,0); read A0,B0(buf1); stage B0(t2)->buf0 (B dead after p2)
    g256_lda(sA1, wm, lm, quad, 0, a0);
    g256_ldb(sB1, wn, lm, quad, 0, bb);
    g256_stage_half(Bg, sB0, w, lane, t2, 0);
    GBAR(); GWAITL();
    g256_mma(acc, a0, bb, 0, 0);
    GBAR();
    // p5: quad(1,0); read A1(buf1); stage B1(t2)->buf0
    g256_lda(sA1, wm, lm, quad, 1, a1);
    g256_stage_half(Bg, sB0, w, lane, t2, 1);
    GBAR(); GWAITL();
    g256_mma(acc, a1, bb, 1, 0);
    GBAR();
    // p6: quad(1,1); read B1(buf1); stage A0(t3)->buf1 (buf1 A dead after p5)
    g256_ldb(sB1, wn, lm, quad, 1, bb);
    g256_stage_half(Ag, sA1, w, lane, t3, 0);
    GBAR(); GWAITL();
    g256_mma(acc, a1, bb, 1, 1);
    GBAR();
    // p7: quad(0,1); stage A1(t3)->buf1; vmcnt(4) certifies tile t2 landed
    g256_stage_half(Ag, sA1, w, lane, t3, 1);
    asm volatile("s_waitcnt vmcnt(4)" ::: "memory");
    GBAR(); GWAITL();
    g256_mma(acc, a0, bb, 0, 1);
    GBAR();
  }
  asm volatile("s_waitcnt vmcnt(0)" ::: "memory");  // drain clamped prefetches
}

// QKV projection (8-phase 256^2): Q,K -> [B,H,S,Dh]; V -> TRANSPOSED [B,H,Dh,S]
__global__ __launch_bounds__(512, 2) void gemm_qkv(const bf16* __restrict__ X,
                                                   const bf16* __restrict__ W,
                                                   bf16* __restrict__ Q,
                                                   bf16* __restrict__ Kv,
                                                   bf16* __restrict__ VT) {
  __shared__ __align__(16) bf16 sA[2][256 * 64];
  __shared__ __align__(16) bf16 sB[2][256 * 64];
  const int t = threadIdx.x, w = t >> 6, lane = t & 63;
  const int lm = lane & 15, quad = lane >> 4;
  const int wm = w >> 2, wn = w & 3;
  // T1 XCD swizzle: 384 wgs, 48 per XCD chunk
  const int bid = blockIdx.x;
  const int swz = (bid & 7) * 48 + (bid >> 3);
  const int bm = swz / 24, bn = swz % 24;
  const int rowBase = bm * 256, colBase = bn * 256;

  f32x4 acc[8][4];
  f32x4 z = {0.f, 0.f, 0.f, 0.f};
#pragma unroll
  for (int i = 0; i < 8; i++)
#pragma unroll
    for (int j = 0; j < 4; j++) acc[i][j] = z;

  gemm256_mainloop(X + (size_t)rowBase * 2048, W + (size_t)colBase * 2048,
                   sA[0], sA[1], sB[0], sB[1], acc, w, lane, wm, wn, lm, quad);

  const int which = colBase >> 11;  // 0=Q 1=K 2=V
  if (which < 2) {
    bf16* dst = which ? Kv : Q;
#pragma unroll
    for (int fi = 0; fi < 8; fi++)
#pragma unroll
      for (int gj = 0; gj < 4; gj++) {
        const int mb = rowBase + wm * 128 + fi * 16 + quad * 4;
        const int nc = (colBase + wn * 64 + gj * 16 + lm) & 2047;
        const int hh = nc >> 7, d = nc & 127;
#pragma unroll
        for (int r = 0; r < 4; r++) {
          const int m = mb + r;
          const int b = m >> 11, s = m & 2047;
          dst[(((size_t)(b * N_HEADS + hh) * SEQ) + s) * HEAD_DIM + d] =
              f2b(acc[fi][gj][r]);
        }
      }
  } else {
#pragma unroll
    for (int fi = 0; fi < 8; fi++)
#pragma unroll
      for (int gj = 0; gj < 4; gj++) {
        const int mb = rowBase + wm * 128 + fi * 16 + quad * 4;
        const int nc = (colBase + wn * 64 + gj * 16 + lm) & 2047;
        const int hh = nc >> 7, d = nc & 127;
        const int b = mb >> 11, s = mb & 2047;
        bf16x4 pk;
#pragma unroll
        for (int r = 0; r < 4; r++) pk[r] = f2b(acc[fi][gj][r]);
        *(bf16x4*)&VT[((size_t)(b * N_HEADS + hh) * HEAD_DIM + d) * SEQ + s] = pk;
      }
  }
}

// ------------------------------------------------- m97-style 128x128x32 mainloop
// (kept for gemm_out: its 256^2 grid would be 128 blocks < 256 CUs — half idle)
__device__ __forceinline__ void gemm_tile_mainloop(
    const bf16* __restrict__ A, const bf16* __restrict__ Bw, int K,
    int rowBase, int colBase, bf16* lA, bf16* lB, f32x4 acc[4][4]) {
  const int t = threadIdx.x;
  const int w = t >> 6, lane = t & 63;
  const int lm = lane & 15, quad = lane >> 4;
  const int wr = (w >> 1) * 64, wc = (w & 1) * 64;

  for (int kt = 0; kt < K; kt += 32) {
#pragma unroll
    for (int i = 0; i < 2; i++) {
      const int c = i * 256 + t;
      const int r = c >> 2, cc = (c & 3) << 3;
      async16(A + (size_t)(rowBase + r) * K + (kt + cc), lA + (i * 256 + w * 64) * 8);
      async16(Bw + (size_t)(colBase + r) * K + (kt + cc), lB + (i * 256 + w * 64) * 8);
    }
    asm volatile("s_waitcnt vmcnt(0)" ::: "memory");
    __syncthreads();
    bf16x8 af[4], bfr[4];
#pragma unroll
    for (int f = 0; f < 4; f++)
      af[f] = *(const bf16x8*)(lA + (wr + f * 16 + lm) * 32 + quad * 8);
#pragma unroll
    for (int f = 0; f < 4; f++)
      bfr[f] = *(const bf16x8*)(lB + (wc + f * 16 + lm) * 32 + quad * 8);
#pragma unroll
    for (int fr = 0; fr < 4; fr++)
#pragma unroll
      for (int fc = 0; fc < 4; fc++)
        acc[fr][fc] = MFMA16(af[fr], bfr[fc], acc[fr][fc]);
    __syncthreads();
  }
}

// Output projection
__global__ __launch_bounds__(256) void gemm_out(const bf16* __restrict__ A,
                                                const bf16* __restrict__ W,
                                                float* __restrict__ out) {
  __shared__ __align__(16) bf16 lA[128 * 32];
  __shared__ __align__(16) bf16 lB[128 * 32];
  f32x4 acc[4][4];
  f32x4 z = {0.f, 0.f, 0.f, 0.f};
#pragma unroll
  for (int i = 0; i < 4; i++)
#pragma unroll
    for (int j = 0; j < 4; j++) acc[i][j] = z;

  const int rowBase = blockIdx.y * 128, colBase = blockIdx.x * 128;
  gemm_tile_mainloop(A, W, DIM, rowBase, colBase, lA, lB, acc);

  const int t = threadIdx.x, w = t >> 6, lane = t & 63;
  const int lm = lane & 15, quad = lane >> 4;
  const int wr = (w >> 1) * 64, wc = (w & 1) * 64;
#pragma unroll
  for (int fr = 0; fr < 4; fr++)
#pragma unroll
    for (int fc = 0; fc < 4; fc++)
#pragma unroll
      for (int r = 0; r < 4; r++) {
        int m = rowBase + wr + fr * 16 + quad * 4 + r;
        int n = colBase + wc + fc * 16 + lm;
        out[(size_t)m * DIM + n] = acc[fr][fc][r];
      }
}

// --------------------------------------------- RMSNorm + RoPE (in place on q,k)
__global__ __launch_bounds__(256) void norm_rope(bf16* __restrict__ Q,
                                                 bf16* __restrict__ K,
                                                 const float* __restrict__ rope,
                                                 const float* __restrict__ qw,
                                                 const float* __restrict__ kw) {
  const int t = threadIdx.x, w = t >> 6, lane = t & 63;
  const int rid = blockIdx.x * 4 + w;
  const int which = rid >> 16;          // 0 = q, 1 = k
  const int row = rid & 65535;          // (b*16+h)*2048 + s
  bf16* ptr = (which ? K : Q) + (size_t)row * HEAD_DIM;
  const float* nw = which ? kw : qw;
  const int s = row & (SEQ - 1);

  float x0 = (float)ptr[lane];
  float x1 = (float)ptr[lane + 64];
  float ss = x0 * x0 + x1 * x1;
#pragma unroll
  for (int off = 32; off; off >>= 1) ss += __shfl_xor(ss, off);
  float r = rsqrtf(ss * (1.f / 128.f) + 1e-6f);
  float x0n = x0 * r * nw[lane];
  float x1n = x1 * r * nw[lane + 64];
  float4 f = ((const float4*)rope)[s * 64 + lane];
  float y0 = f.x * x0n + f.y * x1n;
  float y1 = f.z * x0n + f.w * x1n;
  if (!which) { y0 *= QSCALE_L2E; y1 *= QSCALE_L2E; }
  ptr[lane] = f2b(y0);
  ptr[lane + 64] = f2b(y1);
}

// --------------------------------------------------------- flash attention v9
// (unchanged from R4 — measured win: each wave owns 32 q-rows x 128 keys,
// 2 barriers per 128-key tile, reg-staged prefetch one compute phase ahead,
// bh%8 XCD pinning, exp2-domain static-max softmax, direct store epilogue)
__global__ __launch_bounds__(256, 2) void attn_kernel(const bf16* __restrict__ Q,
                                                      const bf16* __restrict__ K,
                                                      const bf16* __restrict__ VT,
                                                      bf16* __restrict__ O) {
  __shared__ __align__(16) bf16 Ks[128 * 128];   // [k-row][d-chunk ^ (row&15)]
  __shared__ __align__(16) bf16 Vs[128 * 128];   // [d-row][k-chunk ^ (row&15)]

  const int t = threadIdx.x, w = t >> 6, lane = t & 63;
  const int lq = lane & 31, h = lane >> 5;
  const int bh = blockIdx.x, qt = blockIdx.y;

  bf16x8 qf[8];
  {
    const bf16* Qp = Q + ((size_t)bh * SEQ + qt * 128 + w * 32 + lq) * HEAD_DIM;
#pragma unroll
    for (int ks = 0; ks < 8; ks++)
      qf[ks] = *(const bf16x8*)(Qp + ks * 16 + h * 8);
  }

  f32x16 oacc[4];
#pragma unroll
  for (int nb = 0; nb < 4; nb++)
#pragma unroll
    for (int e = 0; e < 16; e++) oacc[nb][e] = 0.f;
  float rsum = 0.f;

  const bf16* kbase = K + (size_t)bh * SEQ * HEAD_DIM;
  const bf16* vbase = VT + (size_t)bh * HEAD_DIM * SEQ;

  const int srow = w * 32 + (lane >> 4), scc = lane & 15;
  bf16x8 kreg[8], vreg[8];

  auto load_tile = [&](int j) {
    const bf16* kp = kbase + (size_t)j * 128 * HEAD_DIM;
    const bf16* vp = vbase + j * 128;
#pragma unroll
    for (int i = 0; i < 8; i++)
      kreg[i] = *(const bf16x8*)(kp + (size_t)(srow + i * 4) * HEAD_DIM + scc * 8);
#pragma unroll
    for (int i = 0; i < 8; i++)
      vreg[i] = *(const bf16x8*)(vp + (size_t)(srow + i * 4) * SEQ + scc * 8);
  };

  load_tile(0);

  for (int j = 0; j < SEQ / 128; j++) {
#pragma unroll
    for (int i = 0; i < 8; i++) {
      int r = srow + i * 4;
      *(bf16x8*)&Ks[r * 128 + ((scc ^ (r & 15)) << 3)] = kreg[i];
    }
#pragma unroll
    for (int i = 0; i < 8; i++) {
      int d = srow + i * 4;
      *(bf16x8*)&Vs[d * 128 + ((scc ^ (d & 15)) << 3)] = vreg[i];
    }
    __syncthreads();

    if (j + 1 < SEQ / 128) load_tile(j + 1);

#pragma unroll
    for (int bp = 0; bp < 2; bp++) {
      f32x16 sacc[2];
#pragma unroll
      for (int bb = 0; bb < 2; bb++)
#pragma unroll
        for (int e = 0; e < 16; e++) sacc[bb][e] = -SMAX_L2E;
      const int r0 = bp * 64 + lq, r1 = r0 + 32;
#pragma unroll
      for (int ks = 0; ks < 8; ks++) {
        int c = ks * 2 + h;
        bf16x8 kf0 = *(const bf16x8*)&Ks[r0 * 128 + ((c ^ (r0 & 15)) << 3)];
        bf16x8 kf1 = *(const bf16x8*)&Ks[r1 * 128 + ((c ^ (r1 & 15)) << 3)];
        sacc[0] = __builtin_amdgcn_mfma_f32_32x32x16_bf16(kf0, qf[ks], sacc[0], 0, 0, 0);
        sacc[1] = __builtin_amdgcn_mfma_f32_32x32x16_bf16(kf1, qf[ks], sacc[1], 0, 0, 0);
      }

      uint32_t a1[2][4], a2[2][4];
#pragma unroll
      for (int bb = 0; bb < 2; bb++) {
        float e[16];
        float p0 = 0.f, p1 = 0.f, p2 = 0.f, p3 = 0.f;
#pragma unroll
        for (int r = 0; r < 16; r += 4) {
          e[r]     = __builtin_amdgcn_exp2f(sacc[bb][r]);
          e[r + 1] = __builtin_amdgcn_exp2f(sacc[bb][r + 1]);
          e[r + 2] = __builtin_amdgcn_exp2f(sacc[bb][r + 2]);
          e[r + 3] = __builtin_amdgcn_exp2f(sacc[bb][r + 3]);
          p0 += e[r]; p1 += e[r + 1]; p2 += e[r + 2]; p3 += e[r + 3];
        }
        rsum += (p0 + p1) + (p2 + p3);
        uint32_t pk[8];
#pragma unroll
        for (int i = 0; i < 8; i++) pk[i] = pack2(e[2 * i], e[2 * i + 1]);
        uint32_t ta = h ? pk[0] : pk[2], tb = h ? pk[1] : pk[3];
        uint32_t tc = h ? pk[4] : pk[6], td = h ? pk[5] : pk[7];
        uint32_t ra = __shfl_xor((int)ta, 32), rb = __shfl_xor((int)tb, 32);
        uint32_t rc = __shfl_xor((int)tc, 32), rd = __shfl_xor((int)td, 32);
        a1[bb][0] = h ? ra : pk[0]; a1[bb][1] = h ? rb : pk[1];
        a1[bb][2] = h ? pk[2] : ra; a1[bb][3] = h ? pk[3] : rb;
        a2[bb][0] = h ? rc : pk[4]; a2[bb][1] = h ? rd : pk[5];
        a2[bb][2] = h ? pk[6] : rc; a2[bb][3] = h ? pk[7] : rd;
      }

#pragma unroll
      for (int bb = 0; bb < 2; bb++)
#pragma unroll
        for (int ks2 = 0; ks2 < 2; ks2++) {
          union { uint32_t u[4]; bf16x8 v; } ap;
#pragma unroll
          for (int i = 0; i < 4; i++) ap.u[i] = ks2 ? a2[bb][i] : a1[bb][i];
          int c2 = (bp * 2 + bb) * 4 + ks2 * 2 + h;
#pragma unroll
          for (int nb = 0; nb < 4; nb++) {
            int rv = nb * 32 + lq;
            bf16x8 bv = *(const bf16x8*)&Vs[rv * 128 + ((c2 ^ (rv & 15)) << 3)];
            oacc[nb] = __builtin_amdgcn_mfma_f32_32x32x16_bf16(ap.v, bv, oacc[nb], 0, 0, 0);
          }
        }
    }
    __syncthreads();
  }

  rsum += __shfl_xor(rsum, 32);
  float inv = 1.f / rsum;
  const int b = bh >> 4, hh = bh & 15;
#pragma unroll
  for (int nb = 0; nb < 4; nb++)
#pragma unroll
    for (int r = 0; r < 16; r++) {
      int q = (r & 3) + 8 * (r >> 2) + 4 * h;
      float iv = __shfl(inv, q);
      int qg = qt * 128 + w * 32 + q;
      O[((size_t)b * SEQ + qg) * DIM + hh * HEAD_DIM + nb * 32 + lq] = f2b(oacc[nb][r] * iv);
    }
}

extern "C" void kernel_launch(void* const* d_in, const int* in_sizes, int n_in,
                              void* d_out, int out_size, void* d_ws, size_t ws_size,
                              hipStream_t stream) {
  const float* x    = (const float*)d_in[0];
  const float* rope = (const float*)d_in[1];
  const float* Wq   = (const float*)d_in[2];
  const float* Wk   = (const float*)d_in[3];
  const float* Wv   = (const float*)d_in[4];
  const float* Wo   = (const float*)d_in[5];
  const float* qw   = (const float*)d_in[6];
  const float* kw   = (const float*)d_in[7];
  float* out = (float*)d_out;

  char* ws = (char*)d_ws;
  bf16* xb   = (bf16*)ws;                        // 16 MB; reused as attn-out
  bf16* wqkv = (bf16*)(ws + (16u << 20));        // 24 MB
  bf16* wo   = (bf16*)(ws + (40u << 20));        // 8 MB
  bf16* qb   = (bf16*)(ws + (48u << 20));        // 16 MB [B,H,S,Dh]
  bf16* kb   = (bf16*)(ws + (64u << 20));        // 16 MB [B,H,S,Dh]
  bf16* vt   = (bf16*)(ws + (80u << 20));        // 16 MB [B,H,Dh,S]
  bf16* attn = xb;

  const int NX = MROWS * DIM;
  const int NW = DIM * DIM;

  cvt_kernel<<<NX / 8 / 256, 256, 0, stream>>>(x, xb, NX);
  cvt_w4<<<4 * (NW / 8 / 256), 256, 0, stream>>>(Wq, Wk, Wv, Wo, wqkv, wo);

  gemm_qkv<<<(MROWS / 256) * (NQKV / 256), 512, 0, stream>>>(xb, wqkv, qb, kb, vt);
  norm_rope<<<(2 * BATCH * N_HEADS * SEQ) / 4, 256, 0, stream>>>(qb, kb, rope, qw, kw);
  attn_kernel<<<dim3(BATCH * N_HEADS, SEQ / 128), 256, 0, stream>>>(qb, kb, vt, attn);
  gemm_out<<<dim3(DIM / 128, MROWS / 128), 256, 0, stream>>>(attn, wo, out);
}

// Round 6
// 415.454 us; speedup vs baseline: 1.4530x; 1.0021x over previous
//
#include <hip/hip_runtime.h>
#include <hip/hip_bf16.h>
#include <stdint.h>

typedef __bf16 bf16;
typedef __bf16 bf16x4 __attribute__((ext_vector_type(4)));
typedef __bf16 bf16x8 __attribute__((ext_vector_type(8)));
typedef float f32x4 __attribute__((ext_vector_type(4)));
typedef float f32x16 __attribute__((ext_vector_type(16)));

#define N_HEADS 16
#define HEAD_DIM 128
#define SEQ 2048
#define DIM 2048
#define BATCH 2
#define MROWS (BATCH * SEQ)          // 4096
#define NQKV (3 * DIM)               // 6144
#define SM_SCALE 0.08838834764831845f   // 1/sqrt(128)
// exp2-domain softmax: Q pre-scaled by SM_SCALE*log2(e); bias = SMAX*log2(e)
#define QSCALE_L2E 0.12751743343563824f // SM_SCALE * 1.4426950408889634
#define SMAX_L2E 34.624680981335122f    // 24.0 * log2(e)

#define MFMA16(a, b, c) __builtin_amdgcn_mfma_f32_16x16x32_bf16(a, b, c, 0, 0, 0)

__device__ __forceinline__ bf16 f2b(float f) {
  union { __hip_bfloat16 h; bf16 b; } u;
  u.h = __float2bfloat16(f);
  return u.b;
}

__device__ __forceinline__ uint32_t pack2(float a, float b) {
  union { __hip_bfloat16 h; unsigned short s; } ua, ub;
  ua.h = __float2bfloat16(a); ub.h = __float2bfloat16(b);
  return (uint32_t)ua.s | ((uint32_t)ub.s << 16);   // a in low 16 (even k)
}

// async global->LDS (lane-contiguous LDS dest; per-lane global source)
__device__ __forceinline__ void async16(const bf16* g, bf16* l) {
  __builtin_amdgcn_global_load_lds(
      (__attribute__((address_space(1))) void*)(uintptr_t)g,
      (__attribute__((address_space(3))) void*)(uintptr_t)l,
      16, 0, 0);
}

// ---------------------------------------------------------------- cvt f32->bf16
__global__ __launch_bounds__(256) void cvt_kernel(const float* __restrict__ src,
                                                  bf16* __restrict__ dst, int n) {
  int i = (blockIdx.x * 256 + threadIdx.x) * 8;
  if (i >= n) return;
  float4 a = *(const float4*)(src + i);
  float4 b = *(const float4*)(src + i + 4);
  bf16x8 o;
  o[0] = f2b(a.x); o[1] = f2b(a.y); o[2] = f2b(a.z); o[3] = f2b(a.w);
  o[4] = f2b(b.x); o[5] = f2b(b.y); o[6] = f2b(b.z); o[7] = f2b(b.w);
  *(bf16x8*)(dst + i) = o;
}

// fused cvt of the 4 weight matrices; w0..w2 -> wqkv, w3 -> wo
__global__ __launch_bounds__(256) void cvt_w4(const float* __restrict__ w0,
                                              const float* __restrict__ w1,
                                              const float* __restrict__ w2,
                                              const float* __restrict__ w3,
                                              bf16* __restrict__ wqkv,
                                              bf16* __restrict__ wo) {
  const int per = (DIM * DIM) / 8 / 256;
  int which = blockIdx.x / per;
  int i = (blockIdx.x % per) * 256 * 8 + threadIdx.x * 8;
  const float* src = which == 0 ? w0 : which == 1 ? w1 : which == 2 ? w2 : w3;
  bf16* dst = which < 3 ? wqkv + (size_t)which * DIM * DIM : wo;
  float4 a = *(const float4*)(src + i);
  float4 b = *(const float4*)(src + i + 4);
  bf16x8 o;
  o[0] = f2b(a.x); o[1] = f2b(a.y); o[2] = f2b(a.z); o[3] = f2b(a.w);
  o[4] = f2b(b.x); o[5] = f2b(b.y); o[6] = f2b(b.z); o[7] = f2b(b.w);
  *(bf16x8*)(dst + i) = o;
}

// ============================== 256x128x64 4-phase GEMM (T2+T3+T4+T5) =========
// R5 post-mortem: 256^2 tile -> grid 384 = 1.5 rounds (25% tail idle). R6:
// BM=256, BN=128 -> grid 768 = EXACTLY 3.0 rounds. 8 waves (4M x 2N), wave
// out 64x64 (acc 64 AGPR, half of R5). Per K-tile = 2 phases x 16 MFMA
// (p0: read all A + B-half0; p1: read B-half1, reuse live a[4][2]) — same
// MFMA-per-barrier density as m201. LDS = 2x(A 256x64 + B 128x64) = 96 KB.
// T2: linear LDS dest + inverse-swizzled global source (chunk^=row&7), same
// XOR on ds_read — verified conflict-free in R5 (SQ_LDS_BANK_CONFLICT=0).
// Stage schedule (steady state; deaths certified by post-MFMA barriers):
//   p0: stage B(t1)->b1          (B(b1) died prev-p3; read this p2)
//   p1: stage A(t2)->b0, vmcnt(4) (A(b0) died p0; drains A(t1)+B(t1) for p2)
//   p2: stage B(t2)->b0          (B(b0) died p1; read next p0)
//   p3: stage A(t3)->b1, vmcnt(4) (A(b1) died p2; drains A(t2)+B(t2) for p0')
// Each vmcnt(4) leaves exactly 4 loads in flight. Clamped tail stages land
// only in dead regions; final vmcnt(0) drains.

#define GBAR() asm volatile("s_barrier" ::: "memory")
#define GWAITL() do { asm volatile("s_waitcnt lgkmcnt(0)" ::: "memory"); \
                      __builtin_amdgcn_sched_barrier(0); } while (0)

// stage 128 rows [rowoff, rowoff+128) of a K-tile t; 2 loads/lane (8 KB/instr
// across 512 threads). LDS linear; global chunk inverse-swizzled (rule #21).
__device__ __forceinline__ void g_stage128(const bf16* gbase, bf16* lbase,
                                           int w, int lane, int t, int rowoff) {
#pragma unroll
  for (int i = 0; i < 2; i++) {
    const int rbase = rowoff + w * 16 + i * 8;
    const int r = rbase + (lane >> 3);
    async16(gbase + (size_t)r * 2048 + t * 64 + 8 * ((lane & 7) ^ (r & 7)),
            lbase + rbase * 64);
  }
}
__device__ __forceinline__ void g_stageA(const bf16* Ag, bf16* sA,
                                         int w, int lane, int t) {
  g_stage128(Ag, sA, w, lane, t, 0);
  g_stage128(Ag, sA, w, lane, t, 128);
}
__device__ __forceinline__ void g_stageB(const bf16* Bg, bf16* sB,
                                         int w, int lane, int t) {
  g_stage128(Bg, sB, w, lane, t, 0);
}

__device__ __forceinline__ void g_lda(const bf16* lbase, int wm, int lm,
                                      int quad, bf16x8 a[4][2]) {
#pragma unroll
  for (int f = 0; f < 4; f++) {
    const int row = wm * 64 + f * 16 + lm;
    const char* p = (const char*)lbase + row * 128;
    const int sw = (row & 7) << 4;
#pragma unroll
    for (int s = 0; s < 2; s++)
      a[f][s] = *(const bf16x8*)(p + ((s * 64 + quad * 16) ^ sw));
  }
}

__device__ __forceinline__ void g_ldb(const bf16* lbase, int wn, int nh, int lm,
                                      int quad, bf16x8 bb[2][2]) {
#pragma unroll
  for (int g = 0; g < 2; g++) {
    const int row = wn * 64 + nh * 32 + g * 16 + lm;
    const char* p = (const char*)lbase + row * 128;
    const int sw = (row & 7) << 4;
#pragma unroll
    for (int s = 0; s < 2; s++)
      bb[g][s] = *(const bf16x8*)(p + ((s * 64 + quad * 16) ^ sw));
  }
}

__device__ __forceinline__ void g_mma(f32x4 acc[4][4], bf16x8 a[4][2],
                                      bf16x8 bb[2][2], int nh) {
  __builtin_amdgcn_s_setprio(1);
#pragma unroll
  for (int s = 0; s < 2; s++)
#pragma unroll
    for (int f = 0; f < 4; f++)
#pragma unroll
      for (int g = 0; g < 2; g++)
        acc[f][nh * 2 + g] = MFMA16(a[f][s], bb[g][s], acc[f][nh * 2 + g]);
  __builtin_amdgcn_s_setprio(0);
}

// QKV projection (4-phase 256x128): Q,K -> [B,H,S,Dh]; V -> [B,H,Dh,S]
__global__ __launch_bounds__(512, 2) void gemm_qkv(const bf16* __restrict__ X,
                                                   const bf16* __restrict__ W,
                                                   bf16* __restrict__ Q,
                                                   bf16* __restrict__ Kv,
                                                   bf16* __restrict__ VT) {
  __shared__ __align__(16) bf16 sA[2][256 * 64];   // 64 KB
  __shared__ __align__(16) bf16 sB[2][128 * 64];   // 32 KB
  const int t = threadIdx.x, w = t >> 6, lane = t & 63;
  const int lm = lane & 15, quad = lane >> 4;
  const int wm = w >> 1, wn = w & 1;
  // XCD swizzle: 768 wgs = 8 chunks of 96 = 8 rect chunks (8 bm x 12 bn)
  const int bid = blockIdx.x;
  const int xcd = bid & 7, loc = bid >> 3;
  const int bm = (xcd >> 2) * 8 + loc / 12;
  const int bn = (xcd & 3) * 12 + loc % 12;
  const int rowBase = bm * 256, colBase = bn * 128;

  f32x4 acc[4][4];
  f32x4 z = {0.f, 0.f, 0.f, 0.f};
#pragma unroll
  for (int i = 0; i < 4; i++)
#pragma unroll
    for (int j = 0; j < 4; j++) acc[i][j] = z;

  const bf16* Ag = X + (size_t)rowBase * 2048;
  const bf16* Bg = W + (size_t)colBase * 2048;

  // prologue: A(t0),B(t0)->b0; A(t1)->b1  (B(t1) staged in-loop at p0)
  g_stageA(Ag, sA[0], w, lane, 0);
  g_stageB(Bg, sB[0], w, lane, 0);
  g_stageA(Ag, sA[1], w, lane, 1);
  asm volatile("s_waitcnt vmcnt(0)" ::: "memory");
  GBAR();

  bf16x8 a[4][2], bb[2][2];

  for (int i = 0; i < 16; i++) {
    const int t1 = 2 * i + 1;
    const int t2 = t1 + 1 < 32 ? t1 + 1 : 31;   // clamped prefetch tiles
    const int t3 = t1 + 2 < 32 ? t1 + 2 : 31;
    // p0 [tile 2i, nh0]: read A(b0)+B(b0,h0); stage B(t1)->b1
    g_lda(sA[0], wm, lm, quad, a);
    g_ldb(sB[0], wn, 0, lm, quad, bb);
    g_stageB(Bg, sB[1], w, lane, t1);
    GBAR(); GWAITL();
    g_mma(acc, a, bb, 0);
    GBAR();
    // p1 [tile 2i, nh1]: read B(b0,h1); stage A(t2)->b0; vmcnt(4)
    g_ldb(sB[0], wn, 1, lm, quad, bb);
    g_stageA(Ag, sA[0], w, lane, t2);
    asm volatile("s_waitcnt vmcnt(4)" ::: "memory");
    GBAR(); GWAITL();
    g_mma(acc, a, bb, 1);
    GBAR();
    // p2 [tile 2i+1, nh0]: read A(b1)+B(b1,h0); stage B(t2)->b0
    g_lda(sA[1], wm, lm, quad, a);
    g_ldb(sB[1], wn, 0, lm, quad, bb);
    g_stageB(Bg, sB[0], w, lane, t2);
    GBAR(); GWAITL();
    g_mma(acc, a, bb, 0);
    GBAR();
    // p3 [tile 2i+1, nh1]: read B(b1,h1); stage A(t3)->b1; vmcnt(4)
    g_ldb(sB[1], wn, 1, lm, quad, bb);
    g_stageA(Ag, sA[1], w, lane, t3);
    asm volatile("s_waitcnt vmcnt(4)" ::: "memory");
    GBAR(); GWAITL();
    g_mma(acc, a, bb, 1);
    GBAR();
  }
  asm volatile("s_waitcnt vmcnt(0)" ::: "memory");  // drain clamped prefetches

  const int which = colBase >> 11;  // 0=Q 1=K 2=V
  if (which < 2) {
    bf16* dst = which ? Kv : Q;
#pragma unroll
    for (int fi = 0; fi < 4; fi++)
#pragma unroll
      for (int gj = 0; gj < 4; gj++) {
        const int mb = rowBase + wm * 64 + fi * 16 + quad * 4;
        const int nc = (colBase + wn * 64 + gj * 16 + lm) & 2047;
        const int hh = nc >> 7, d = nc & 127;
#pragma unroll
        for (int r = 0; r < 4; r++) {
          const int m = mb + r;
          const int b = m >> 11, s = m & 2047;
          dst[(((size_t)(b * N_HEADS + hh) * SEQ) + s) * HEAD_DIM + d] =
              f2b(acc[fi][gj][r]);
        }
      }
  } else {
#pragma unroll
    for (int fi = 0; fi < 4; fi++)
#pragma unroll
      for (int gj = 0; gj < 4; gj++) {
        const int mb = rowBase + wm * 64 + fi * 16 + quad * 4;
        const int nc = (colBase + wn * 64 + gj * 16 + lm) & 2047;
        const int hh = nc >> 7, d = nc & 127;
        const int b = mb >> 11, s = mb & 2047;
        bf16x4 pk;
#pragma unroll
        for (int r = 0; r < 4; r++) pk[r] = f2b(acc[fi][gj][r]);
        *(bf16x4*)&VT[((size_t)(b * N_HEADS + hh) * HEAD_DIM + d) * SEQ + s] = pk;
      }
  }
}

// ------------------------------------------------- m97-style 128x128x32 mainloop
// (kept for gemm_out: its 256^2 grid would be 128 blocks < 256 CUs — half idle)
__device__ __forceinline__ void gemm_tile_mainloop(
    const bf16* __restrict__ A, const bf16* __restrict__ Bw, int K,
    int rowBase, int colBase, bf16* lA, bf16* lB, f32x4 acc[4][4]) {
  const int t = threadIdx.x;
  const int w = t >> 6, lane = t & 63;
  const int lm = lane & 15, quad = lane >> 4;
  const int wr = (w >> 1) * 64, wc = (w & 1) * 64;

  for (int kt = 0; kt < K; kt += 32) {
#pragma unroll
    for (int i = 0; i < 2; i++) {
      const int c = i * 256 + t;
      const int r = c >> 2, cc = (c & 3) << 3;
      async16(A + (size_t)(rowBase + r) * K + (kt + cc), lA + (i * 256 + w * 64) * 8);
      async16(Bw + (size_t)(colBase + r) * K + (kt + cc), lB + (i * 256 + w * 64) * 8);
    }
    asm volatile("s_waitcnt vmcnt(0)" ::: "memory");
    __syncthreads();
    bf16x8 af[4], bfr[4];
#pragma unroll
    for (int f = 0; f < 4; f++)
      af[f] = *(const bf16x8*)(lA + (wr + f * 16 + lm) * 32 + quad * 8);
#pragma unroll
    for (int f = 0; f < 4; f++)
      bfr[f] = *(const bf16x8*)(lB + (wc + f * 16 + lm) * 32 + quad * 8);
#pragma unroll
    for (int fr = 0; fr < 4; fr++)
#pragma unroll
      for (int fc = 0; fc < 4; fc++)
        acc[fr][fc] = MFMA16(af[fr], bfr[fc], acc[fr][fc]);
    __syncthreads();
  }
}

// Output projection
__global__ __launch_bounds__(256) void gemm_out(const bf16* __restrict__ A,
                                                const bf16* __restrict__ W,
                                                float* __restrict__ out) {
  __shared__ __align__(16) bf16 lA[128 * 32];
  __shared__ __align__(16) bf16 lB[128 * 32];
  f32x4 acc[4][4];
  f32x4 z = {0.f, 0.f, 0.f, 0.f};
#pragma unroll
  for (int i = 0; i < 4; i++)
#pragma unroll
    for (int j = 0; j < 4; j++) acc[i][j] = z;

  const int rowBase = blockIdx.y * 128, colBase = blockIdx.x * 128;
  gemm_tile_mainloop(A, W, DIM, rowBase, colBase, lA, lB, acc);

  const int t = threadIdx.x, w = t >> 6, lane = t & 63;
  const int lm = lane & 15, quad = lane >> 4;
  const int wr = (w >> 1) * 64, wc = (w & 1) * 64;
#pragma unroll
  for (int fr = 0; fr < 4; fr++)
#pragma unroll
    for (int fc = 0; fc < 4; fc++)
#pragma unroll
      for (int r = 0; r < 4; r++) {
        int m = rowBase + wr + fr * 16 + quad * 4 + r;
        int n = colBase + wc + fc * 16 + lm;
        out[(size_t)m * DIM + n] = acc[fr][fc][r];
      }
}

// --------------------------------------------- RMSNorm + RoPE (in place on q,k)
__global__ __launch_bounds__(256) void norm_rope(bf16* __restrict__ Q,
                                                 bf16* __restrict__ K,
                                                 const float* __restrict__ rope,
                                                 const float* __restrict__ qw,
                                                 const float* __restrict__ kw) {
  const int t = threadIdx.x, w = t >> 6, lane = t & 63;
  const int rid = blockIdx.x * 4 + w;
  const int which = rid >> 16;          // 0 = q, 1 = k
  const int row = rid & 65535;          // (b*16+h)*2048 + s
  bf16* ptr = (which ? K : Q) + (size_t)row * HEAD_DIM;
  const float* nw = which ? kw : qw;
  const int s = row & (SEQ - 1);

  float x0 = (float)ptr[lane];
  float x1 = (float)ptr[lane + 64];
  float ss = x0 * x0 + x1 * x1;
#pragma unroll
  for (int off = 32; off; off >>= 1) ss += __shfl_xor(ss, off);
  float r = rsqrtf(ss * (1.f / 128.f) + 1e-6f);
  float x0n = x0 * r * nw[lane];
  float x1n = x1 * r * nw[lane + 64];
  float4 f = ((const float4*)rope)[s * 64 + lane];
  float y0 = f.x * x0n + f.y * x1n;
  float y1 = f.z * x0n + f.w * x1n;
  if (!which) { y0 *= QSCALE_L2E; y1 *= QSCALE_L2E; }
  ptr[lane] = f2b(y0);
  ptr[lane + 64] = f2b(y1);
}

// --------------------------------------------------------- flash attention v9
// (unchanged — measured win: each wave owns 32 q-rows x 128 keys, 2 barriers
// per 128-key tile, reg-staged prefetch one compute phase ahead, bh%8 XCD
// pinning, exp2-domain static-max softmax, direct store epilogue)
__global__ __launch_bounds__(256, 2) void attn_kernel(const bf16* __restrict__ Q,
                                                      const bf16* __restrict__ K,
                                                      const bf16* __restrict__ VT,
                                                      bf16* __restrict__ O) {
  __shared__ __align__(16) bf16 Ks[128 * 128];   // [k-row][d-chunk ^ (row&15)]
  __shared__ __align__(16) bf16 Vs[128 * 128];   // [d-row][k-chunk ^ (row&15)]

  const int t = threadIdx.x, w = t >> 6, lane = t & 63;
  const int lq = lane & 31, h = lane >> 5;
  const int bh = blockIdx.x, qt = blockIdx.y;

  bf16x8 qf[8];
  {
    const bf16* Qp = Q + ((size_t)bh * SEQ + qt * 128 + w * 32 + lq) * HEAD_DIM;
#pragma unroll
    for (int ks = 0; ks < 8; ks++)
      qf[ks] = *(const bf16x8*)(Qp + ks * 16 + h * 8);
  }

  f32x16 oacc[4];
#pragma unroll
  for (int nb = 0; nb < 4; nb++)
#pragma unroll
    for (int e = 0; e < 16; e++) oacc[nb][e] = 0.f;
  float rsum = 0.f;

  const bf16* kbase = K + (size_t)bh * SEQ * HEAD_DIM;
  const bf16* vbase = VT + (size_t)bh * HEAD_DIM * SEQ;

  const int srow = w * 32 + (lane >> 4), scc = lane & 15;
  bf16x8 kreg[8], vreg[8];

  auto load_tile = [&](int j) {
    const bf16* kp = kbase + (size_t)j * 128 * HEAD_DIM;
    const bf16* vp = vbase + j * 128;
#pragma unroll
    for (int i = 0; i < 8; i++)
      kreg[i] = *(const bf16x8*)(kp + (size_t)(srow + i * 4) * HEAD_DIM + scc * 8);
#pragma unroll
    for (int i = 0; i < 8; i++)
      vreg[i] = *(const bf16x8*)(vp + (size_t)(srow + i * 4) * SEQ + scc * 8);
  };

  load_tile(0);

  for (int j = 0; j < SEQ / 128; j++) {
#pragma unroll
    for (int i = 0; i < 8; i++) {
      int r = srow + i * 4;
      *(bf16x8*)&Ks[r * 128 + ((scc ^ (r & 15)) << 3)] = kreg[i];
    }
#pragma unroll
    for (int i = 0; i < 8; i++) {
      int d = srow + i * 4;
      *(bf16x8*)&Vs[d * 128 + ((scc ^ (d & 15)) << 3)] = vreg[i];
    }
    __syncthreads();

    if (j + 1 < SEQ / 128) load_tile(j + 1);

#pragma unroll
    for (int bp = 0; bp < 2; bp++) {
      f32x16 sacc[2];
#pragma unroll
      for (int bb = 0; bb < 2; bb++)
#pragma unroll
        for (int e = 0; e < 16; e++) sacc[bb][e] = -SMAX_L2E;
      const int r0 = bp * 64 + lq, r1 = r0 + 32;
#pragma unroll
      for (int ks = 0; ks < 8; ks++) {
        int c = ks * 2 + h;
        bf16x8 kf0 = *(const bf16x8*)&Ks[r0 * 128 + ((c ^ (r0 & 15)) << 3)];
        bf16x8 kf1 = *(const bf16x8*)&Ks[r1 * 128 + ((c ^ (r1 & 15)) << 3)];
        sacc[0] = __builtin_amdgcn_mfma_f32_32x32x16_bf16(kf0, qf[ks], sacc[0], 0, 0, 0);
        sacc[1] = __builtin_amdgcn_mfma_f32_32x32x16_bf16(kf1, qf[ks], sacc[1], 0, 0, 0);
      }

      uint32_t a1[2][4], a2[2][4];
#pragma unroll
      for (int bb = 0; bb < 2; bb++) {
        float e[16];
        float p0 = 0.f, p1 = 0.f, p2 = 0.f, p3 = 0.f;
#pragma unroll
        for (int r = 0; r < 16; r += 4) {
          e[r]     = __builtin_amdgcn_exp2f(sacc[bb][r]);
          e[r + 1] = __builtin_amdgcn_exp2f(sacc[bb][r + 1]);
          e[r + 2] = __builtin_amdgcn_exp2f(sacc[bb][r + 2]);
          e[r + 3] = __builtin_amdgcn_exp2f(sacc[bb][r + 3]);
          p0 += e[r]; p1 += e[r + 1]; p2 += e[r + 2]; p3 += e[r + 3];
        }
        rsum += (p0 + p1) + (p2 + p3);
        uint32_t pk[8];
#pragma unroll
        for (int i = 0; i < 8; i++) pk[i] = pack2(e[2 * i], e[2 * i + 1]);
        uint32_t ta = h ? pk[0] : pk[2], tb = h ? pk[1] : pk[3];
        uint32_t tc = h ? pk[4] : pk[6], td = h ? pk[5] : pk[7];
        uint32_t ra = __shfl_xor((int)ta, 32), rb = __shfl_xor((int)tb, 32);
        uint32_t rc = __shfl_xor((int)tc, 32), rd = __shfl_xor((int)td, 32);
        a1[bb][0] = h ? ra : pk[0]; a1[bb][1] = h ? rb : pk[1];
        a1[bb][2] = h ? pk[2] : ra; a1[bb][3] = h ? pk[3] : rb;
        a2[bb][0] = h ? rc : pk[4]; a2[bb][1] = h ? rd : pk[5];
        a2[bb][2] = h ? pk[6] : rc; a2[bb][3] = h ? pk[7] : rd;
      }

#pragma unroll
      for (int bb = 0; bb < 2; bb++)
#pragma unroll
        for (int ks2 = 0; ks2 < 2; ks2++) {
          union { uint32_t u[4]; bf16x8 v; } ap;
#pragma unroll
          for (int i = 0; i < 4; i++) ap.u[i] = ks2 ? a2[bb][i] : a1[bb][i];
          int c2 = (bp * 2 + bb) * 4 + ks2 * 2 + h;
#pragma unroll
          for (int nb = 0; nb < 4; nb++) {
            int rv = nb * 32 + lq;
            bf16x8 bv = *(const bf16x8*)&Vs[rv * 128 + ((c2 ^ (rv & 15)) << 3)];
            oacc[nb] = __builtin_amdgcn_mfma_f32_32x32x16_bf16(ap.v, bv, oacc[nb], 0, 0, 0);
          }
        }
    }
    __syncthreads();
  }

  rsum += __shfl_xor(rsum, 32);
  float inv = 1.f / rsum;
  const int b = bh >> 4, hh = bh & 15;
#pragma unroll
  for (int nb = 0; nb < 4; nb++)
#pragma unroll
    for (int r = 0; r < 16; r++) {
      int q = (r & 3) + 8 * (r >> 2) + 4 * h;
      float iv = __shfl(inv, q);
      int qg = qt * 128 + w * 32 + q;
      O[((size_t)b * SEQ + qg) * DIM + hh * HEAD_DIM + nb * 32 + lq] = f2b(oacc[nb][r] * iv);
    }
}

extern "C" void kernel_launch(void* const* d_in, const int* in_sizes, int n_in,
                              void* d_out, int out_size, void* d_ws, size_t ws_size,
                              hipStream_t stream) {
  const float* x    = (const float*)d_in[0];
  const float* rope = (const float*)d_in[1];
  const float* Wq   = (const float*)d_in[2];
  const float* Wk   = (const float*)d_in[3];
  const float* Wv   = (const float*)d_in[4];
  const float* Wo   = (const float*)d_in[5];
  const float* qw   = (const float*)d_in[6];
  const float* kw   = (const float*)d_in[7];
  float* out = (float*)d_out;

  char* ws = (char*)d_ws;
  bf16* xb   = (bf16*)ws;                        // 16 MB; reused as attn-out
  bf16* wqkv = (bf16*)(ws + (16u << 20));        // 24 MB
  bf16* wo   = (bf16*)(ws + (40u << 20));        // 8 MB
  bf16* qb   = (bf16*)(ws + (48u << 20));        // 16 MB [B,H,S,Dh]
  bf16* kb   = (bf16*)(ws + (64u << 20));        // 16 MB [B,H,S,Dh]
  bf16* vt   = (bf16*)(ws + (80u << 20));        // 16 MB [B,H,Dh,S]
  bf16* attn = xb;

  const int NX = MROWS * DIM;
  const int NW = DIM * DIM;

  cvt_kernel<<<NX / 8 / 256, 256, 0, stream>>>(x, xb, NX);
  cvt_w4<<<4 * (NW / 8 / 256), 256, 0, stream>>>(Wq, Wk, Wv, Wo, wqkv, wo);

  gemm_qkv<<<(MROWS / 256) * (NQKV / 128), 512, 0, stream>>>(xb, wqkv, qb, kb, vt);
  norm_rope<<<(2 * BATCH * N_HEADS * SEQ) / 4, 256, 0, stream>>>(qb, kb, rope, qw, kw);
  attn_kernel<<<dim3(BATCH * N_HEADS, SEQ / 128), 256, 0, stream>>>(qb, kb, vt, attn);
  gemm_out<<<dim3(DIM / 128, MROWS / 128), 256, 0, stream>>>(attn, wo, out);
}

// Round 7
// 384.450 us; speedup vs baseline: 1.5701x; 1.0806x over previous
//
#include <hip/hip_runtime.h>
#include <hip/hip_bf16.h>
#include <stdint.h>

typedef __bf16 bf16;
typedef __bf16 bf16x4 __attribute__((ext_vector_type(4)));
typedef __bf16 bf16x8 __attribute__((ext_vector_type(8)));
typedef float f32x4 __attribute__((ext_vector_type(4)));
typedef float f32x16 __attribute__((ext_vector_type(16)));

#define N_HEADS 16
#define HEAD_DIM 128
#define SEQ 2048
#define DIM 2048
#define BATCH 2
#define MROWS (BATCH * SEQ)          // 4096
#define NQKV (3 * DIM)               // 6144
#define SM_SCALE 0.08838834764831845f   // 1/sqrt(128)
// exp2-domain softmax: Q pre-scaled by SM_SCALE*log2(e); bias = SMAX*log2(e)
#define QSCALE_L2E 0.12751743343563824f // SM_SCALE * 1.4426950408889634
#define SMAX_L2E 34.624680981335122f    // 24.0 * log2(e)

#define MFMA16(a, b, c) __builtin_amdgcn_mfma_f32_16x16x32_bf16(a, b, c, 0, 0, 0)

__device__ __forceinline__ bf16 f2b(float f) {
  union { __hip_bfloat16 h; bf16 b; } u;
  u.h = __float2bfloat16(f);
  return u.b;
}

__device__ __forceinline__ uint32_t pack2(float a, float b) {
  union { __hip_bfloat16 h; unsigned short s; } ua, ub;
  ua.h = __float2bfloat16(a); ub.h = __float2bfloat16(b);
  return (uint32_t)ua.s | ((uint32_t)ub.s << 16);   // a in low 16 (even k)
}

// async global->LDS (lane-contiguous LDS dest; per-lane global source)
__device__ __forceinline__ void async16(const bf16* g, bf16* l) {
  __builtin_amdgcn_global_load_lds(
      (__attribute__((address_space(1))) void*)(uintptr_t)g,
      (__attribute__((address_space(3))) void*)(uintptr_t)l,
      16, 0, 0);
}

// ------------------------------------------- fused cvt f32->bf16 (x + 4 weights)
__global__ __launch_bounds__(256) void cvt_all(const float* __restrict__ x,
                                               const float* __restrict__ w0,
                                               const float* __restrict__ w1,
                                               const float* __restrict__ w2,
                                               const float* __restrict__ w3,
                                               bf16* __restrict__ xb,
                                               bf16* __restrict__ wqkv,
                                               bf16* __restrict__ wo) {
  const int NX = MROWS * DIM;        // 2^23
  const int NW = DIM * DIM;          // 2^22
  int e = (blockIdx.x * 256 + threadIdx.x) * 8;
  const float* src;
  bf16* dst;
  if (e < NX) {
    src = x + e; dst = xb + e;
  } else {
    int e2 = e - NX;
    int which = e2 >> 22, off = e2 & (NW - 1);
    src = (which == 0 ? w0 : which == 1 ? w1 : which == 2 ? w2 : w3) + off;
    dst = (which < 3 ? wqkv + (size_t)which * NW : wo) + off;
  }
  float4 a = *(const float4*)src;
  float4 b = *(const float4*)(src + 4);
  bf16x8 o;
  o[0] = f2b(a.x); o[1] = f2b(a.y); o[2] = f2b(a.z); o[3] = f2b(a.w);
  o[4] = f2b(b.x); o[5] = f2b(b.y); o[6] = f2b(b.z); o[7] = f2b(b.w);
  *(bf16x8*)dst = o;
}

// ============================== 256x128x64 4-phase GEMM (T2+T3+T4+T5) =========
// Verified R5/R6: conflicts=0, refcheck pass. 8 waves (4M x 2N), wave out
// 64x64. Per K-tile = 2 phases x 16 MFMA. LDS = 2x(A 256x64 + B 128x64) =
// 96 KB. T2: linear LDS dest + inverse-swizzled global source (chunk^=row&7),
// same XOR on ds_read. Stage schedule (steady state; deaths certified by
// post-MFMA barriers):
//   p0: stage B(t1)->b1          p1: stage A(t2)->b0, vmcnt(4)
//   p2: stage B(t2)->b0          p3: stage A(t3)->b1, vmcnt(4)
// Each vmcnt(4) leaves exactly 4 loads in flight; clamped tail stages land
// only in dead regions; final vmcnt(0) drains.

#define GBAR() asm volatile("s_barrier" ::: "memory")
#define GWAITL() do { asm volatile("s_waitcnt lgkmcnt(0)" ::: "memory"); \
                      __builtin_amdgcn_sched_barrier(0); } while (0)

__device__ __forceinline__ void g_stage128(const bf16* gbase, bf16* lbase,
                                           int w, int lane, int t, int rowoff) {
#pragma unroll
  for (int i = 0; i < 2; i++) {
    const int rbase = rowoff + w * 16 + i * 8;
    const int r = rbase + (lane >> 3);
    async16(gbase + (size_t)r * 2048 + t * 64 + 8 * ((lane & 7) ^ (r & 7)),
            lbase + rbase * 64);
  }
}
__device__ __forceinline__ void g_stageA(const bf16* Ag, bf16* sA,
                                         int w, int lane, int t) {
  g_stage128(Ag, sA, w, lane, t, 0);
  g_stage128(Ag, sA, w, lane, t, 128);
}
__device__ __forceinline__ void g_stageB(const bf16* Bg, bf16* sB,
                                         int w, int lane, int t) {
  g_stage128(Bg, sB, w, lane, t, 0);
}

__device__ __forceinline__ void g_lda(const bf16* lbase, int wm, int lm,
                                      int quad, bf16x8 a[4][2]) {
#pragma unroll
  for (int f = 0; f < 4; f++) {
    const int row = wm * 64 + f * 16 + lm;
    const char* p = (const char*)lbase + row * 128;
    const int sw = (row & 7) << 4;
#pragma unroll
    for (int s = 0; s < 2; s++)
      a[f][s] = *(const bf16x8*)(p + ((s * 64 + quad * 16) ^ sw));
  }
}

__device__ __forceinline__ void g_ldb(const bf16* lbase, int wn, int nh, int lm,
                                      int quad, bf16x8 bb[2][2]) {
#pragma unroll
  for (int g = 0; g < 2; g++) {
    const int row = wn * 64 + nh * 32 + g * 16 + lm;
    const char* p = (const char*)lbase + row * 128;
    const int sw = (row & 7) << 4;
#pragma unroll
    for (int s = 0; s < 2; s++)
      bb[g][s] = *(const bf16x8*)(p + ((s * 64 + quad * 16) ^ sw));
  }
}

__device__ __forceinline__ void g_mma(f32x4 acc[4][4], bf16x8 a[4][2],
                                      bf16x8 bb[2][2], int nh) {
  __builtin_amdgcn_s_setprio(1);
#pragma unroll
  for (int s = 0; s < 2; s++)
#pragma unroll
    for (int f = 0; f < 4; f++)
#pragma unroll
      for (int g = 0; g < 2; g++)
        acc[f][nh * 2 + g] = MFMA16(a[f][s], bb[g][s], acc[f][nh * 2 + g]);
  __builtin_amdgcn_s_setprio(0);
}

// the full 32-K-tile mainloop (K = 2048), shared by gemm_qkv and gemm_out
__device__ __forceinline__ void gemm4p_mainloop(
    const bf16* __restrict__ Ag, const bf16* __restrict__ Bg,
    bf16* sA0, bf16* sA1, bf16* sB0, bf16* sB1, f32x4 acc[4][4],
    int w, int lane, int wm, int wn, int lm, int quad) {
  // prologue: A(t0),B(t0)->b0; A(t1)->b1  (B(t1) staged in-loop at p0)
  g_stageA(Ag, sA0, w, lane, 0);
  g_stageB(Bg, sB0, w, lane, 0);
  g_stageA(Ag, sA1, w, lane, 1);
  asm volatile("s_waitcnt vmcnt(0)" ::: "memory");
  GBAR();

  bf16x8 a[4][2], bb[2][2];

  for (int i = 0; i < 16; i++) {
    const int t1 = 2 * i + 1;
    const int t2 = t1 + 1 < 32 ? t1 + 1 : 31;   // clamped prefetch tiles
    const int t3 = t1 + 2 < 32 ? t1 + 2 : 31;
    // p0 [tile 2i, nh0]: read A(b0)+B(b0,h0); stage B(t1)->b1
    g_lda(sA0, wm, lm, quad, a);
    g_ldb(sB0, wn, 0, lm, quad, bb);
    g_stageB(Bg, sB1, w, lane, t1);
    GBAR(); GWAITL();
    g_mma(acc, a, bb, 0);
    GBAR();
    // p1 [tile 2i, nh1]: read B(b0,h1); stage A(t2)->b0; vmcnt(4)
    g_ldb(sB0, wn, 1, lm, quad, bb);
    g_stageA(Ag, sA0, w, lane, t2);
    asm volatile("s_waitcnt vmcnt(4)" ::: "memory");
    GBAR(); GWAITL();
    g_mma(acc, a, bb, 1);
    GBAR();
    // p2 [tile 2i+1, nh0]: read A(b1)+B(b1,h0); stage B(t2)->b0
    g_lda(sA1, wm, lm, quad, a);
    g_ldb(sB1, wn, 0, lm, quad, bb);
    g_stageB(Bg, sB0, w, lane, t2);
    GBAR(); GWAITL();
    g_mma(acc, a, bb, 0);
    GBAR();
    // p3 [tile 2i+1, nh1]: read B(b1,h1); stage A(t3)->b1; vmcnt(4)
    g_ldb(sB1, wn, 1, lm, quad, bb);
    g_stageA(Ag, sA1, w, lane, t3);
    asm volatile("s_waitcnt vmcnt(4)" ::: "memory");
    GBAR(); GWAITL();
    g_mma(acc, a, bb, 1);
    GBAR();
  }
  asm volatile("s_waitcnt vmcnt(0)" ::: "memory");  // drain clamped prefetches
}

// QKV projection (4-phase 256x128): Q,K -> [B,H,S,Dh]; V -> [B,H,Dh,S]
__global__ __launch_bounds__(512, 2) void gemm_qkv(const bf16* __restrict__ X,
                                                   const bf16* __restrict__ W,
                                                   bf16* __restrict__ Q,
                                                   bf16* __restrict__ Kv,
                                                   bf16* __restrict__ VT) {
  __shared__ __align__(16) bf16 sA[2][256 * 64];   // 64 KB
  __shared__ __align__(16) bf16 sB[2][128 * 64];   // 32 KB
  const int t = threadIdx.x, w = t >> 6, lane = t & 63;
  const int lm = lane & 15, quad = lane >> 4;
  const int wm = w >> 1, wn = w & 1;
  // XCD swizzle: 768 wgs = 8 rect chunks (8 bm x 12 bn)
  const int bid = blockIdx.x;
  const int xcd = bid & 7, loc = bid >> 3;
  const int bm = (xcd >> 2) * 8 + loc / 12;
  const int bn = (xcd & 3) * 12 + loc % 12;
  const int rowBase = bm * 256, colBase = bn * 128;

  f32x4 acc[4][4];
  f32x4 z = {0.f, 0.f, 0.f, 0.f};
#pragma unroll
  for (int i = 0; i < 4; i++)
#pragma unroll
    for (int j = 0; j < 4; j++) acc[i][j] = z;

  gemm4p_mainloop(X + (size_t)rowBase * 2048, W + (size_t)colBase * 2048,
                  sA[0], sA[1], sB[0], sB[1], acc, w, lane, wm, wn, lm, quad);

  const int which = colBase >> 11;  // 0=Q 1=K 2=V
  if (which < 2) {
    bf16* dst = which ? Kv : Q;
#pragma unroll
    for (int fi = 0; fi < 4; fi++)
#pragma unroll
      for (int gj = 0; gj < 4; gj++) {
        const int mb = rowBase + wm * 64 + fi * 16 + quad * 4;
        const int nc = (colBase + wn * 64 + gj * 16 + lm) & 2047;
        const int hh = nc >> 7, d = nc & 127;
#pragma unroll
        for (int r = 0; r < 4; r++) {
          const int m = mb + r;
          const int b = m >> 11, s = m & 2047;
          dst[(((size_t)(b * N_HEADS + hh) * SEQ) + s) * HEAD_DIM + d] =
              f2b(acc[fi][gj][r]);
        }
      }
  } else {
#pragma unroll
    for (int fi = 0; fi < 4; fi++)
#pragma unroll
      for (int gj = 0; gj < 4; gj++) {
        const int mb = rowBase + wm * 64 + fi * 16 + quad * 4;
        const int nc = (colBase + wn * 64 + gj * 16 + lm) & 2047;
        const int hh = nc >> 7, d = nc & 127;
        const int b = mb >> 11, s = mb & 2047;
        bf16x4 pk;
#pragma unroll
        for (int r = 0; r < 4; r++) pk[r] = f2b(acc[fi][gj][r]);
        *(bf16x4*)&VT[((size_t)(b * N_HEADS + hh) * HEAD_DIM + d) * SEQ + s] = pk;
      }
  }
}

// Output projection (4-phase 256x128): grid 256 blocks = exactly 1.0 rounds
__global__ __launch_bounds__(512, 2) void gemm_out(const bf16* __restrict__ A,
                                                   const bf16* __restrict__ W,
                                                   float* __restrict__ out) {
  __shared__ __align__(16) bf16 sA[2][256 * 64];   // 64 KB
  __shared__ __align__(16) bf16 sB[2][128 * 64];   // 32 KB
  const int t = threadIdx.x, w = t >> 6, lane = t & 63;
  const int lm = lane & 15, quad = lane >> 4;
  const int wm = w >> 1, wn = w & 1;
  // XCD swizzle: 256 wgs = 8 rect chunks (4 bm x 8 bn)
  const int bid = blockIdx.x;
  const int xcd = bid & 7, loc = bid >> 3;
  const int bm = (xcd >> 1) * 4 + (loc >> 3);
  const int bn = (xcd & 1) * 8 + (loc & 7);
  const int rowBase = bm * 256, colBase = bn * 128;

  f32x4 acc[4][4];
  f32x4 z = {0.f, 0.f, 0.f, 0.f};
#pragma unroll
  for (int i = 0; i < 4; i++)
#pragma unroll
    for (int j = 0; j < 4; j++) acc[i][j] = z;

  gemm4p_mainloop(A + (size_t)rowBase * 2048, W + (size_t)colBase * 2048,
                  sA[0], sA[1], sB[0], sB[1], acc, w, lane, wm, wn, lm, quad);

#pragma unroll
  for (int fi = 0; fi < 4; fi++)
#pragma unroll
    for (int gj = 0; gj < 4; gj++) {
      const int mb = rowBase + wm * 64 + fi * 16 + quad * 4;
      const int n = colBase + wn * 64 + gj * 16 + lm;
#pragma unroll
      for (int r = 0; r < 4; r++)
        out[(size_t)(mb + r) * DIM + n] = acc[fi][gj][r];
    }
}

// --------------------------------------------- RMSNorm + RoPE (in place on q,k)
__global__ __launch_bounds__(256) void norm_rope(bf16* __restrict__ Q,
                                                 bf16* __restrict__ K,
                                                 const float* __restrict__ rope,
                                                 const float* __restrict__ qw,
                                                 const float* __restrict__ kw) {
  const int t = threadIdx.x, w = t >> 6, lane = t & 63;
  const int rid = blockIdx.x * 4 + w;
  const int which = rid >> 16;          // 0 = q, 1 = k
  const int row = rid & 65535;          // (b*16+h)*2048 + s
  bf16* ptr = (which ? K : Q) + (size_t)row * HEAD_DIM;
  const float* nw = which ? kw : qw;
  const int s = row & (SEQ - 1);

  float x0 = (float)ptr[lane];
  float x1 = (float)ptr[lane + 64];
  float ss = x0 * x0 + x1 * x1;
#pragma unroll
  for (int off = 32; off; off >>= 1) ss += __shfl_xor(ss, off);
  float r = rsqrtf(ss * (1.f / 128.f) + 1e-6f);
  float x0n = x0 * r * nw[lane];
  float x1n = x1 * r * nw[lane + 64];
  float4 f = ((const float4*)rope)[s * 64 + lane];
  float y0 = f.x * x0n + f.y * x1n;
  float y1 = f.z * x0n + f.w * x1n;
  if (!which) { y0 *= QSCALE_L2E; y1 *= QSCALE_L2E; }
  ptr[lane] = f2b(y0);
  ptr[lane + 64] = f2b(y1);
}

// --------------------------------------------------------- flash attention v9
__global__ __launch_bounds__(256, 2) void attn_kernel(const bf16* __restrict__ Q,
                                                      const bf16* __restrict__ K,
                                                      const bf16* __restrict__ VT,
                                                      bf16* __restrict__ O) {
  __shared__ __align__(16) bf16 Ks[128 * 128];   // [k-row][d-chunk ^ (row&15)]
  __shared__ __align__(16) bf16 Vs[128 * 128];   // [d-row][k-chunk ^ (row&15)]

  const int t = threadIdx.x, w = t >> 6, lane = t & 63;
  const int lq = lane & 31, h = lane >> 5;
  const int bh = blockIdx.x, qt = blockIdx.y;

  bf16x8 qf[8];
  {
    const bf16* Qp = Q + ((size_t)bh * SEQ + qt * 128 + w * 32 + lq) * HEAD_DIM;
#pragma unroll
    for (int ks = 0; ks < 8; ks++)
      qf[ks] = *(const bf16x8*)(Qp + ks * 16 + h * 8);
  }

  f32x16 oacc[4];
#pragma unroll
  for (int nb = 0; nb < 4; nb++)
#pragma unroll
    for (int e = 0; e < 16; e++) oacc[nb][e] = 0.f;
  float rsum = 0.f;

  const bf16* kbase = K + (size_t)bh * SEQ * HEAD_DIM;
  const bf16* vbase = VT + (size_t)bh * HEAD_DIM * SEQ;

  const int srow = w * 32 + (lane >> 4), scc = lane & 15;
  bf16x8 kreg[8], vreg[8];

  auto load_tile = [&](int j) {
    const bf16* kp = kbase + (size_t)j * 128 * HEAD_DIM;
    const bf16* vp = vbase + j * 128;
#pragma unroll
    for (int i = 0; i < 8; i++)
      kreg[i] = *(const bf16x8*)(kp + (size_t)(srow + i * 4) * HEAD_DIM + scc * 8);
#pragma unroll
    for (int i = 0; i < 8; i++)
      vreg[i] = *(const bf16x8*)(vp + (size_t)(srow + i * 4) * SEQ + scc * 8);
  };

  load_tile(0);

  for (int j = 0; j < SEQ / 128; j++) {
#pragma unroll
    for (int i = 0; i < 8; i++) {
      int r = srow + i * 4;
      *(bf16x8*)&Ks[r * 128 + ((scc ^ (r & 15)) << 3)] = kreg[i];
    }
#pragma unroll
    for (int i = 0; i < 8; i++) {
      int d = srow + i * 4;
      *(bf16x8*)&Vs[d * 128 + ((scc ^ (d & 15)) << 3)] = vreg[i];
    }
    __syncthreads();

    if (j + 1 < SEQ / 128) load_tile(j + 1);

#pragma unroll
    for (int bp = 0; bp < 2; bp++) {
      f32x16 sacc[2];
#pragma unroll
      for (int bb = 0; bb < 2; bb++)
#pragma unroll
        for (int e = 0; e < 16; e++) sacc[bb][e] = -SMAX_L2E;
      const int r0 = bp * 64 + lq, r1 = r0 + 32;
#pragma unroll
      for (int ks = 0; ks < 8; ks++) {
        int c = ks * 2 + h;
        bf16x8 kf0 = *(const bf16x8*)&Ks[r0 * 128 + ((c ^ (r0 & 15)) << 3)];
        bf16x8 kf1 = *(const bf16x8*)&Ks[r1 * 128 + ((c ^ (r1 & 15)) << 3)];
        sacc[0] = __builtin_amdgcn_mfma_f32_32x32x16_bf16(kf0, qf[ks], sacc[0], 0, 0, 0);
        sacc[1] = __builtin_amdgcn_mfma_f32_32x32x16_bf16(kf1, qf[ks], sacc[1], 0, 0, 0);
      }

      uint32_t a1[2][4], a2[2][4];
#pragma unroll
      for (int bb = 0; bb < 2; bb++) {
        float e[16];
        float p0 = 0.f, p1 = 0.f, p2 = 0.f, p3 = 0.f;
#pragma unroll
        for (int r = 0; r < 16; r += 4) {
          e[r]     = __builtin_amdgcn_exp2f(sacc[bb][r]);
          e[r + 1] = __builtin_amdgcn_exp2f(sacc[bb][r + 1]);
          e[r + 2] = __builtin_amdgcn_exp2f(sacc[bb][r + 2]);
          e[r + 3] = __builtin_amdgcn_exp2f(sacc[bb][r + 3]);
          p0 += e[r]; p1 += e[r + 1]; p2 += e[r + 2]; p3 += e[r + 3];
        }
        rsum += (p0 + p1) + (p2 + p3);
        uint32_t pk[8];
#pragma unroll
        for (int i = 0; i < 8; i++) pk[i] = pack2(e[2 * i], e[2 * i + 1]);
        uint32_t ta = h ? pk[0] : pk[2], tb = h ? pk[1] : pk[3];
        uint32_t tc = h ? pk[4] : pk[6], td = h ? pk[5] : pk[7];
        uint32_t ra = __shfl_xor((int)ta, 32), rb = __shfl_xor((int)tb, 32);
        uint32_t rc = __shfl_xor((int)tc, 32), rd = __shfl_xor((int)td, 32);
        a1[bb][0] = h ? ra : pk[0]; a1[bb][1] = h ? rb : pk[1];
        a1[bb][2] = h ? pk[2] : ra; a1[bb][3] = h ? pk[3] : rb;
        a2[bb][0] = h ? rc : pk[4]; a2[bb][1] = h ? rd : pk[5];
        a2[bb][2] = h ? pk[6] : rc; a2[bb][3] = h ? pk[7] : rd;
      }

#pragma unroll
      for (int bb = 0; bb < 2; bb++)
#pragma unroll
        for (int ks2 = 0; ks2 < 2; ks2++) {
          union { uint32_t u[4]; bf16x8 v; } ap;
#pragma unroll
          for (int i = 0; i < 4; i++) ap.u[i] = ks2 ? a2[bb][i] : a1[bb][i];
          int c2 = (bp * 2 + bb) * 4 + ks2 * 2 + h;
#pragma unroll
          for (int nb = 0; nb < 4; nb++) {
            int rv = nb * 32 + lq;
            bf16x8 bv = *(const bf16x8*)&Vs[rv * 128 + ((c2 ^ (rv & 15)) << 3)];
            oacc[nb] = __builtin_amdgcn_mfma_f32_32x32x16_bf16(ap.v, bv, oacc[nb], 0, 0, 0);
          }
        }
    }
    __syncthreads();
  }

  rsum += __shfl_xor(rsum, 32);
  float inv = 1.f / rsum;
  const int b = bh >> 4, hh = bh & 15;
#pragma unroll
  for (int nb = 0; nb < 4; nb++)
#pragma unroll
    for (int r = 0; r < 16; r++) {
      int q = (r & 3) + 8 * (r >> 2) + 4 * h;
      float iv = __shfl(inv, q);
      int qg = qt * 128 + w * 32 + q;
      O[((size_t)b * SEQ + qg) * DIM + hh * HEAD_DIM + nb * 32 + lq] = f2b(oacc[nb][r] * iv);
    }
}

extern "C" void kernel_launch(void* const* d_in, const int* in_sizes, int n_in,
                              void* d_out, int out_size, void* d_ws, size_t ws_size,
                              hipStream_t stream) {
  const float* x    = (const float*)d_in[0];
  const float* rope = (const float*)d_in[1];
  const float* Wq   = (const float*)d_in[2];
  const float* Wk   = (const float*)d_in[3];
  const float* Wv   = (const float*)d_in[4];
  const float* Wo   = (const float*)d_in[5];
  const float* qw   = (const float*)d_in[6];
  const float* kw   = (const float*)d_in[7];
  float* out = (float*)d_out;

  char* ws = (char*)d_ws;
  bf16* xb   = (bf16*)ws;                        // 16 MB; reused as attn-out
  bf16* wqkv = (bf16*)(ws + (16u << 20));        // 24 MB
  bf16* wo   = (bf16*)(ws + (40u << 20));        // 8 MB
  bf16* qb   = (bf16*)(ws + (48u << 20));        // 16 MB [B,H,S,Dh]
  bf16* kb   = (bf16*)(ws + (64u << 20));        // 16 MB [B,H,S,Dh]
  bf16* vt   = (bf16*)(ws + (80u << 20));        // 16 MB [B,H,Dh,S]
  bf16* attn = xb;

  const int NTOT = MROWS * DIM + 4 * DIM * DIM;  // 24M elements

  cvt_all<<<NTOT / 8 / 256, 256, 0, stream>>>(x, Wq, Wk, Wv, Wo, xb, wqkv, wo);

  gemm_qkv<<<(MROWS / 256) * (NQKV / 128), 512, 0, stream>>>(xb, wqkv, qb, kb, vt);
  norm_rope<<<(2 * BATCH * N_HEADS * SEQ) / 4, 256, 0, stream>>>(qb, kb, rope, qw, kw);
  attn_kernel<<<dim3(BATCH * N_HEADS, SEQ / 128), 256, 0, stream>>>(qb, kb, vt, attn);
  gemm_out<<<(MROWS / 256) * (DIM / 128), 512, 0, stream>>>(attn, wo, out);
}